// Round 14
// baseline (1113.620 us; speedup 1.0000x reference)
//
#include <hip/hip_runtime.h>
#include <cstdint>
#include <cstddef>

// ---------------------------------------------------------------------------
// EGT layer.  N nodes (DIM=96, H=32, HD=3), E edges.
// edge_tile_kernel: 64 CSR-ordered edges per block; gathers q[dst],k[src],
// v[src]; MFMA bf16 GEMMs; writes exve5[slot][160]={ex|ex*v|ex*ve} bf16.
// gather: pure streaming segmented sum (no random reads, no indirection).
// mgemm: MFMA node GEMM with fused LN / bf16-A modes.
// ---------------------------------------------------------------------------

typedef short  s16x8 __attribute__((ext_vector_type(8)));
typedef short  s16x4 __attribute__((ext_vector_type(4)));
typedef float  f32x4 __attribute__((ext_vector_type(4)));

__device__ __forceinline__ unsigned short f2b(float x) {
    union { float f; unsigned u; } v; v.f = x;
    unsigned r = v.u + 0x7FFF + ((v.u >> 16) & 1);   // RNE
    return (unsigned short)(r >> 16);
}
__device__ __forceinline__ float b2f(unsigned short u) {
    union { unsigned u; float f; } v; v.u = ((unsigned)u) << 16; return v.f;
}

// ---------------- MFMA node GEMM ----------------
template<int MULTI, int LNA, int A16, int RELU, int RES>
__global__ __launch_bounds__(256) void mgemm_kernel(
    const void* __restrict__ Av, int lda,
    const float* __restrict__ B0, const float* __restrict__ B1,
    const float* __restrict__ B2, int ldb,
    const float* __restrict__ bias0, const float* __restrict__ bias1,
    const float* __restrict__ bias2,
    const float* __restrict__ lng, const float* __restrict__ lnbv,
    const float* __restrict__ resid, const float* __restrict__ wptr,
    float* __restrict__ C, int ldc, unsigned short* __restrict__ C16,
    int M, int K)
{
    __shared__ unsigned short sAL[64 * 200];
    __shared__ unsigned short sB[96 * 40];

    const int tid = threadIdx.x;
    const int m0 = blockIdx.x * 64;
    const int y  = blockIdx.y;
    const float* B = MULTI ? (y == 0 ? B0 : (y == 1 ? B1 : B2)) : B0;
    const int nbB = MULTI ? 0 : y * 96;
    const int nbC = y * 96;
    const int w = tid >> 6, l = tid & 63, fr = l & 15, kg = l >> 4;
    const int KP = K + 8;

    if (LNA) {
        const float* Af = (const float*)Av;
        const int row = 16 * w + fr;
        const int grow = m0 + row;
        float x[24];
        if (grow < M) {
            #pragma unroll
            for (int t = 0; t < 6; t++)
                *(float4*)&x[t * 4] = *(const float4*)(Af + (size_t)grow * lda + 24 * kg + t * 4);
        } else {
            #pragma unroll
            for (int t = 0; t < 24; t++) x[t] = 0.f;
        }
        float s = 0.f;
        #pragma unroll
        for (int t = 0; t < 24; t++) s += x[t];
        s += __shfl_xor(s, 16, 64); s += __shfl_xor(s, 32, 64);
        float mu = s * (1.f / 96.f);
        float v2 = 0.f;
        #pragma unroll
        for (int t = 0; t < 24; t++) { float d = x[t] - mu; v2 += d * d; }
        v2 += __shfl_xor(v2, 16, 64); v2 += __shfl_xor(v2, 32, 64);
        float rs = rsqrtf(v2 * (1.f / 96.f) + 1e-5f);
        #pragma unroll
        for (int t3 = 0; t3 < 3; t3++) {
            s16x8 yv;
            #pragma unroll
            for (int u = 0; u < 8; u++) {
                int cidx = 24 * kg + t3 * 8 + u;
                yv[u] = (short)f2b((x[t3 * 8 + u] - mu) * rs * lng[cidx] + lnbv[cidx]);
            }
            *(s16x8*)&sAL[row * KP + 24 * kg + t3 * 8] = yv;
        }
    } else {
        const int nseg = K >> 3;
        for (int idx = tid; idx < 64 * nseg; idx += 256) {
            int row = idx / nseg, k8 = (idx - row * nseg) * 8;
            int grow = m0 + row;
            s16x8 a8 = (s16x8){0, 0, 0, 0, 0, 0, 0, 0};
            if (grow < M) {
                if (A16) {
                    a8 = *(const s16x8*)((const unsigned short*)Av + (size_t)grow * lda + k8);
                } else {
                    const float* Af = (const float*)Av;
                    float4 v0 = *(const float4*)(Af + (size_t)grow * lda + k8);
                    float4 v1 = *(const float4*)(Af + (size_t)grow * lda + k8 + 4);
                    a8[0] = (short)f2b(v0.x); a8[1] = (short)f2b(v0.y);
                    a8[2] = (short)f2b(v0.z); a8[3] = (short)f2b(v0.w);
                    a8[4] = (short)f2b(v1.x); a8[5] = (short)f2b(v1.y);
                    a8[6] = (short)f2b(v1.z); a8[7] = (short)f2b(v1.w);
                }
            }
            *(s16x8*)&sAL[row * KP + k8] = a8;
        }
    }

    f32x4 acc[6];
    #pragma unroll
    for (int i = 0; i < 6; i++) acc[i] = (f32x4){0.f, 0.f, 0.f, 0.f};

    for (int kc = 0; kc < K; kc += 32) {
        #pragma unroll
        for (int r = 0; r < 3; r++) {
            int idx = tid + 256 * r;
            int k = idx / 24, n4 = (idx - k * 24) * 4;
            float4 v = *(const float4*)(B + (size_t)(kc + k) * ldb + nbB + n4);
            sB[(n4 + 0) * 40 + k] = f2b(v.x);
            sB[(n4 + 1) * 40 + k] = f2b(v.y);
            sB[(n4 + 2) * 40 + k] = f2b(v.z);
            sB[(n4 + 3) * 40 + k] = f2b(v.w);
        }
        __syncthreads();
        {
            s16x8 a = *(s16x8*)&sAL[(16 * w + fr) * KP + kc + kg * 8];
            #pragma unroll
            for (int nt = 0; nt < 6; nt++) {
                s16x8 b = *(s16x8*)&sB[(16 * nt + fr) * 40 + kg * 8];
                acc[nt] = __builtin_amdgcn_mfma_f32_16x16x32_bf16(a, b, acc[nt], 0, 0, 0);
            }
        }
        __syncthreads();
    }

    float scale = 1.f;
    if (RES) scale = wptr ? (1.f + wptr[0]) : 1.f;
    const float* biasp = MULTI ? (y == 0 ? bias0 : (y == 1 ? bias1 : bias2)) : bias0;
    const int bbase = MULTI ? 0 : nbB;

    #pragma unroll
    for (int nt = 0; nt < 6; nt++) {
        int cl = nt * 16 + fr;
        float bv = biasp[bbase + cl];
        int gcol = nbC + cl;
        #pragma unroll
        for (int r = 0; r < 4; r++) {
            int row = m0 + 16 * w + 4 * kg + r;
            if (row >= M) continue;
            float v = acc[nt][r] + bv;
            if (RELU) v = fmaxf(v, 0.f);
            if (RES) v += scale * resid[(size_t)row * ldc + gcol];
            C[(size_t)row * ldc + gcol] = v;
            if (MULTI && C16 != nullptr && y == 2)
                C16[(size_t)row * 96 + cl] = f2b(v);
        }
    }
}

// ---------------- CSR bucketing ----------------
__global__ __launch_bounds__(256) void count_kernel(
    const int* __restrict__ dst, int* __restrict__ cnt, int E)
{
    int i = blockIdx.x * 256 + threadIdx.x;
    if (i < E) atomicAdd(&cnt[dst[i]], 1);
}

__global__ __launch_bounds__(1024) void scan_kernel(
    const int* __restrict__ cnt, int* __restrict__ off, int* __restrict__ cur, int N)
{
    __shared__ int s[1024];
    const int tid = threadIdx.x;
    const int chunk = (N + 1023) >> 10;
    const int lo = tid * chunk;
    const int hi = min(lo + chunk, N);
    int sum = 0;
    for (int i = lo; i < hi; i++) sum += cnt[i];
    s[tid] = sum;
    __syncthreads();
    for (int d = 1; d < 1024; d <<= 1) {
        int v = (tid >= d) ? s[tid - d] : 0;
        __syncthreads();
        s[tid] += v;
        __syncthreads();
    }
    int base = (tid == 0) ? 0 : s[tid - 1];
    for (int i = lo; i < hi; i++) {
        off[i] = base; cur[i] = base;
        base += cnt[i];
    }
}

// scatter: slot arrays eidx/srcs/dsts (CSR order)
__global__ __launch_bounds__(256) void scatter_kernel(
    const int* __restrict__ dst, const int* __restrict__ src,
    int* __restrict__ cur, int* __restrict__ eidx,
    int* __restrict__ srcs, int* __restrict__ dsts, int E)
{
    int i = blockIdx.x * 256 + threadIdx.x;
    if (i < E) {
        int p = atomicAdd(&cur[dst[i]], 1);
        eidx[p] = i;
        srcs[p] = src[i];
        dsts[p] = dst[i];
    }
}

// ---------------- edge tile kernel: 64 CSR slots per block ------------------
// exve5[slot][160] bf16 = { ex[0:32) | ex*v[32:128) | ex*ve[128:160) }
__global__ __launch_bounds__(256, 3) void edge_tile_kernel(
    const float* __restrict__ edge, const float* __restrict__ qkv,
    const int* __restrict__ eidx, const int* __restrict__ srcs,
    const int* __restrict__ dsts,
    const float* __restrict__ We, const float* __restrict__ be,
    const float* __restrict__ Wb, const float* __restrict__ bb,
    const float* __restrict__ Wf0, const float* __restrict__ bf0,
    const float* __restrict__ Wf1, const float* __restrict__ bf1,
    const float* __restrict__ ge0, const float* __restrict__ be0,
    const float* __restrict__ ge1, const float* __restrict__ be1,
    unsigned short* __restrict__ exve5, float* __restrict__ eout, int E)
{
    __shared__ float          sEV[64 * 36];   // ev -> er
    __shared__ unsigned short sQK[64 * 44];   // qk bf16 (pad 44: conflict-free)
    __shared__ unsigned short sA [64 * 40];   // ew/en bf16
    __shared__ unsigned short sB [64 * 40];   // Wb|We then Wf0
    __shared__ unsigned short sB2[32 * 72];   // Wf1^T
    __shared__ unsigned short sX [64 * 76];   // ex|ve then F (pad 76)
    __shared__ unsigned short sV [64 * 100];  // v[src] rows bf16
    // total 52224 B -> 3 blocks/CU

    const int tid = threadIdx.x;
    const long long e0 = (long long)blockIdx.x * 64;
    const int w  = tid >> 6;
    const int l  = tid & 63;
    const int fr = l & 15;
    const int kg = l >> 4;

    // ---- S1a: score (4 threads/slot) + v staging ----
    {
        const int row = tid >> 2;
        const int j   = tid & 3;
        long long s = e0 + row;
        float q[24], k[24];
        int sn = 0;
        if (s < E) {
            int dn = dsts[s]; sn = srcs[s];
            const float* qp = qkv + (size_t)dn * 288 + 24 * j;
            const float* kp = qkv + (size_t)sn * 288 + 96 + 24 * j;
            #pragma unroll
            for (int t = 0; t < 6; t++) {
                *(float4*)&q[t * 4] = *(const float4*)(qp + t * 4);
                *(float4*)&k[t * 4] = *(const float4*)(kp + t * 4);
            }
        } else {
            #pragma unroll
            for (int t = 0; t < 24; t++) { q[t] = 0.f; k[t] = 0.f; }
        }
        s16x8 qkb;
        #pragma unroll
        for (int t = 0; t < 8; t++) {
            float d = k[3*t]*q[3*t] + k[3*t+1]*q[3*t+1] + k[3*t+2]*q[3*t+2];
            qkb[t] = (short)f2b(0.5f * d);
        }
        *(s16x8*)&sQK[row * 44 + 8 * j] = qkb;
        // v rows -> sV (bf16), 24 values per thread
        if (s < E) {
            const float* vp = qkv + (size_t)sn * 288 + 192 + 24 * j;
            #pragma unroll
            for (int t = 0; t < 3; t++) {
                float4 v0 = *(const float4*)(vp + t * 8);
                float4 v1 = *(const float4*)(vp + t * 8 + 4);
                s16x8 vb;
                vb[0] = (short)f2b(v0.x); vb[1] = (short)f2b(v0.y);
                vb[2] = (short)f2b(v0.z); vb[3] = (short)f2b(v0.w);
                vb[4] = (short)f2b(v1.x); vb[5] = (short)f2b(v1.y);
                vb[6] = (short)f2b(v1.z); vb[7] = (short)f2b(v1.w);
                *(s16x8*)&sV[row * 100 + 24 * j + 8 * t] = vb;
            }
        }
    }

    // ---- S1b: stage ev (gathered via eidx), Wb|We^T, Wf1^T ----
    #pragma unroll
    for (int rr = 0; rr < 2; rr++) {
        int idx = tid + 256 * rr;
        int row = idx >> 3, c4 = (idx & 7) * 4;
        long long s = e0 + row;
        float4 v = make_float4(0.f, 0.f, 0.f, 0.f);
        if (s < E) {
            int ge = eidx[s];
            v = *(const float4*)(edge + (size_t)ge * 32 + c4);
        }
        *(float4*)&sEV[row * 36 + c4] = v;
    }
    {
        int k = tid >> 3, c4 = (tid & 7) * 4;
        float4 vb = *(const float4*)(Wb + k * 32 + c4);
        float4 ve = *(const float4*)(We + k * 32 + c4);
        sB[(c4 + 0) * 40 + k] = f2b(vb.x); sB[(c4 + 1) * 40 + k] = f2b(vb.y);
        sB[(c4 + 2) * 40 + k] = f2b(vb.z); sB[(c4 + 3) * 40 + k] = f2b(vb.w);
        sB[(32 + c4 + 0) * 40 + k] = f2b(ve.x); sB[(32 + c4 + 1) * 40 + k] = f2b(ve.y);
        sB[(32 + c4 + 2) * 40 + k] = f2b(ve.z); sB[(32 + c4 + 3) * 40 + k] = f2b(ve.w);
    }
    #pragma unroll
    for (int rr = 0; rr < 2; rr++) {
        int idx = tid + 256 * rr;
        int k = idx >> 3, c4 = (idx & 7) * 4;
        float4 v = *(const float4*)(Wf1 + k * 32 + c4);
        sB2[(c4 + 0) * 72 + k] = f2b(v.x); sB2[(c4 + 1) * 72 + k] = f2b(v.y);
        sB2[(c4 + 2) * 72 + k] = f2b(v.z); sB2[(c4 + 3) * 72 + k] = f2b(v.w);
    }
    __syncthreads();

    // ---- S2: LN1 -> ew rows (bf16) in sA ----
    {
        const int row = 16 * w + (tid & 15);
        const int q = (tid & 63) >> 4;
        float x[8];
        *(float4*)&x[0] = *(float4*)&sEV[row * 36 + 8 * q];
        *(float4*)&x[4] = *(float4*)&sEV[row * 36 + 8 * q + 4];
        float s = x[0] + x[1] + x[2] + x[3] + x[4] + x[5] + x[6] + x[7];
        s += __shfl_xor(s, 16, 64); s += __shfl_xor(s, 32, 64);
        float mu = s * (1.f / 32.f);
        float v2 = 0.f;
        #pragma unroll
        for (int i = 0; i < 8; i++) { float d = x[i] - mu; v2 += d * d; }
        v2 += __shfl_xor(v2, 16, 64); v2 += __shfl_xor(v2, 32, 64);
        float rs = rsqrtf(v2 * (1.f / 32.f) + 1e-5f);
        float4 g1 = *(const float4*)(ge0 + 8 * q), g2 = *(const float4*)(ge0 + 8 * q + 4);
        float4 b1 = *(const float4*)(be0 + 8 * q), b2 = *(const float4*)(be0 + 8 * q + 4);
        float gg[8] = {g1.x, g1.y, g1.z, g1.w, g2.x, g2.y, g2.z, g2.w};
        float bs[8] = {b1.x, b1.y, b1.z, b1.w, b2.x, b2.y, b2.z, b2.w};
        s16x8 y;
        #pragma unroll
        for (int i = 0; i < 8; i++)
            y[i] = (short)f2b((x[i] - mu) * rs * gg[i] + bs[i]);
        *(s16x8*)&sA[row * 40 + 8 * q] = y;
    }
    __syncthreads();

    // ---- S3: GEMM1 (MFMA)  [64][64 = sc|veh] = ew @ [Wb|We] ----
    f32x4 acc[4];
    {
        s16x8 a = *(s16x8*)&sA[(16 * w + fr) * 40 + kg * 8];
        #pragma unroll
        for (int nt = 0; nt < 4; nt++) {
            s16x8 b = *(s16x8*)&sB[(16 * nt + fr) * 40 + kg * 8];
            f32x4 z = {0.f, 0.f, 0.f, 0.f};
            acc[nt] = __builtin_amdgcn_mfma_f32_16x16x32_bf16(a, b, z, 0, 0, 0);
        }
    }
    __syncthreads();

    // ---- S4: epilogue1 (ex|ve -> sX; er -> sEV) + restage Wf0 -> sB ----
    #pragma unroll
    for (int nt = 0; nt < 2; nt++) {
        int col = nt * 16 + fr;
        float bbv = bb[col];
        #pragma unroll
        for (int r = 0; r < 4; r++) {
            int row = 16 * w + 4 * kg + r;
            float sc = acc[nt][r] + b2f(sQK[row * 44 + col]) + bbv;
            sX[row * 76 + col] = f2b(__expf(sc));
            float er = sc + sEV[row * 36 + col];
            sEV[row * 36 + col] = er;
        }
    }
    #pragma unroll
    for (int nt = 2; nt < 4; nt++) {
        int col = (nt - 2) * 16 + fr;
        float bev = be[col];
        #pragma unroll
        for (int r = 0; r < 4; r++) {
            int row = 16 * w + 4 * kg + r;
            sX[row * 76 + 32 + col] = f2b(acc[nt][r] + bev);
        }
    }
    #pragma unroll
    for (int rr = 0; rr < 2; rr++) {
        int idx = tid + 256 * rr;
        int k = idx >> 4, c4 = (idx & 15) * 4;
        float4 v = *(const float4*)(Wf0 + k * 64 + c4);
        sB[(c4 + 0) * 40 + k] = f2b(v.x); sB[(c4 + 1) * 40 + k] = f2b(v.y);
        sB[(c4 + 2) * 40 + k] = f2b(v.z); sB[(c4 + 3) * 40 + k] = f2b(v.w);
    }
    __syncthreads();

    // ---- S5: exve5 writes (contiguous at slot) + LN2 (er -> en in sA) ----
    {
        const int row = tid >> 2;
        const int j   = tid & 3;
        long long s = e0 + row;
        if (s < E) {
            unsigned short* base = exve5 + (size_t)s * 160;
            if (j == 0) {
                #pragma unroll
                for (int t = 0; t < 4; t++)
                    *(s16x8*)(base + 8 * t) = *(s16x8*)&sX[row * 76 + 8 * t];
            } else if (j == 3) {
                #pragma unroll
                for (int t = 0; t < 4; t++) {
                    s16x8 o;
                    #pragma unroll
                    for (int u = 0; u < 8; u++) {
                        int h = 8 * t + u;
                        o[u] = (short)f2b(b2f(sX[row * 76 + h]) * b2f(sX[row * 76 + 32 + h]));
                    }
                    *(s16x8*)(base + 128 + 8 * t) = o;
                }
            } else {
                const int m0 = (j - 1) * 48;
                #pragma unroll
                for (int t = 0; t < 6; t++) {
                    s16x8 o;
                    #pragma unroll
                    for (int u = 0; u < 8; u++) {
                        int m = m0 + 8 * t + u;
                        o[u] = (short)f2b(b2f(sX[row * 76 + m / 3]) * b2f(sV[row * 100 + m]));
                    }
                    *(s16x8*)(base + 32 + m0 + 8 * t) = o;
                }
            }
        }
    }
    {
        const int row = 16 * w + (tid & 15);
        const int q = (tid & 63) >> 4;
        float x[8];
        *(float4*)&x[0] = *(float4*)&sEV[row * 36 + 8 * q];
        *(float4*)&x[4] = *(float4*)&sEV[row * 36 + 8 * q + 4];
        float s = x[0] + x[1] + x[2] + x[3] + x[4] + x[5] + x[6] + x[7];
        s += __shfl_xor(s, 16, 64); s += __shfl_xor(s, 32, 64);
        float mu = s * (1.f / 32.f);
        float v2 = 0.f;
        #pragma unroll
        for (int i = 0; i < 8; i++) { float d = x[i] - mu; v2 += d * d; }
        v2 += __shfl_xor(v2, 16, 64); v2 += __shfl_xor(v2, 32, 64);
        float rs = rsqrtf(v2 * (1.f / 32.f) + 1e-5f);
        float4 g1 = *(const float4*)(ge1 + 8 * q), g2 = *(const float4*)(ge1 + 8 * q + 4);
        float4 b1 = *(const float4*)(be1 + 8 * q), b2 = *(const float4*)(be1 + 8 * q + 4);
        float gg[8] = {g1.x, g1.y, g1.z, g1.w, g2.x, g2.y, g2.z, g2.w};
        float bs[8] = {b1.x, b1.y, b1.z, b1.w, b2.x, b2.y, b2.z, b2.w};
        s16x8 y;
        #pragma unroll
        for (int i = 0; i < 8; i++)
            y[i] = (short)f2b((x[i] - mu) * rs * gg[i] + bs[i]);
        *(s16x8*)&sA[row * 40 + 8 * q] = y;
    }
    __syncthreads();

    // ---- S6: GEMM2 (MFMA)  F[64][64] = relu(en @ Wf0 + bf0) -> sX ----
    {
        s16x8 a = *(s16x8*)&sA[(16 * w + fr) * 40 + kg * 8];
        #pragma unroll
        for (int nt = 0; nt < 4; nt++) {
            s16x8 b = *(s16x8*)&sB[(16 * nt + fr) * 40 + kg * 8];
            f32x4 z = {0.f, 0.f, 0.f, 0.f};
            f32x4 a2 = __builtin_amdgcn_mfma_f32_16x16x32_bf16(a, b, z, 0, 0, 0);
            int col = nt * 16 + fr;
            float b0v = bf0[col];
            #pragma unroll
            for (int r = 0; r < 4; r++) {
                int row = 16 * w + 4 * kg + r;
                sX[row * 76 + col] = f2b(fmaxf(a2[r] + b0v, 0.f));
            }
        }
    }
    __syncthreads();

    // ---- S7: GEMM3 (MFMA)  out[64][32] = F @ Wf1 + er + bf1 -> sEV ----
    {
        s16x8 a0 = *(s16x8*)&sX[(16 * w + fr) * 76 + kg * 8];
        s16x8 a1 = *(s16x8*)&sX[(16 * w + fr) * 76 + 32 + kg * 8];
        #pragma unroll
        for (int nt = 0; nt < 2; nt++) {
            s16x8 b0 = *(s16x8*)&sB2[(16 * nt + fr) * 72 + kg * 8];
            s16x8 b1 = *(s16x8*)&sB2[(16 * nt + fr) * 72 + 32 + kg * 8];
            f32x4 z = {0.f, 0.f, 0.f, 0.f};
            f32x4 t = __builtin_amdgcn_mfma_f32_16x16x32_bf16(a0, b0, z, 0, 0, 0);
            t = __builtin_amdgcn_mfma_f32_16x16x32_bf16(a1, b1, t, 0, 0, 0);
            int col = nt * 16 + fr;
            float bf1v = bf1[col];
            #pragma unroll
            for (int r = 0; r < 4; r++) {
                int row = 16 * w + 4 * kg + r;
                float out = t[r] + sEV[row * 36 + col] + bf1v;
                sEV[row * 36 + col] = out;
            }
        }
    }
    __syncthreads();

    // ---- S8: copy sEV[:, 0..32) -> eout[eidx[s]] ----
    #pragma unroll
    for (int rr = 0; rr < 2; rr++) {
        int idx = tid + 256 * rr;
        int row = idx >> 3, c4 = (idx & 7) * 4;
        long long s = e0 + row;
        if (s < E) {
            int ge = eidx[s];
            *(float4*)(eout + (size_t)ge * 32 + c4) = *(float4*)&sEV[row * 36 + c4];
        }
    }
}

// ---------------- gather: streaming segmented sum over exve5 ---------------
__global__ __launch_bounds__(256) void gather_kernel(
    const unsigned short* __restrict__ exve5,
    const int* __restrict__ off, const int* __restrict__ cnt,
    unsigned short* __restrict__ agg16, int N)
{
    __shared__ float red[4][176];
    const int wave = threadIdx.x >> 6;
    const int lane = threadIdx.x & 63;
    int n = blockIdx.x * 4 + wave;
    if (n >= N) return;
    const int o = off[n], d = cnt[n];
    const unsigned* base = (const unsigned*)exve5 + (size_t)o * 80;
    float s0 = 0.f, s1 = 0.f, s2 = 0.f, s3 = 0.f;
    for (int i = 0; i < d; i++) {
        unsigned wv = base[(size_t)i * 80 + lane];
        s0 += b2f((unsigned short)(wv & 0xFFFFu));
        s1 += b2f((unsigned short)(wv >> 16));
        if (lane < 16) {
            unsigned w2 = base[(size_t)i * 80 + 64 + lane];
            s2 += b2f((unsigned short)(w2 & 0xFFFFu));
            s3 += b2f((unsigned short)(w2 >> 16));
        }
    }
    red[wave][2 * lane]     = s0;
    red[wave][2 * lane + 1] = s1;
    if (lane < 16) {
        red[wave][128 + 2 * lane] = s2;
        red[wave][129 + 2 * lane] = s3;
    }
    __builtin_amdgcn_wave_barrier();
    if (lane < 32) {
        float den = red[wave][lane];
        float r = (d > 0 && den != 0.f) ? 1.f / den : 0.f;
        s16x4 ov;
        ov[0] = (short)f2b(red[wave][32 + 3 * lane] * r);
        ov[1] = (short)f2b(red[wave][33 + 3 * lane] * r);
        ov[2] = (short)f2b(red[wave][34 + 3 * lane] * r);
        ov[3] = (short)f2b(red[wave][128 + lane] * r);
        *(s16x4*)(agg16 + (size_t)n * 128 + lane * 4) = ov;
    }
}

// ---------------------------------------------------------------------------
extern "C" void kernel_launch(void* const* d_in, const int* in_sizes, int n_in,
                              void* d_out, int out_size, void* d_ws, size_t ws_size,
                              hipStream_t stream)
{
    (void)n_in; (void)out_size; (void)ws_size;
    const float* feat = (const float*)d_in[0];
    const float* edge = (const float*)d_in[1];
    const float* Wq   = (const float*)d_in[2];
    const float* bq   = (const float*)d_in[3];
    const float* Wk   = (const float*)d_in[4];
    const float* bk   = (const float*)d_in[5];
    const float* Wv   = (const float*)d_in[6];
    const float* bv   = (const float*)d_in[7];
    const float* We   = (const float*)d_in[8];
    const float* be   = (const float*)d_in[9];
    const float* Wb   = (const float*)d_in[10];
    const float* bb   = (const float*)d_in[11];
    const float* Wvv  = (const float*)d_in[12];
    const float* bvv  = (const float*)d_in[13];
    const float* Wf0  = (const float*)d_in[14];
    const float* bf0  = (const float*)d_in[15];
    const float* Wf1  = (const float*)d_in[16];
    const float* bf1  = (const float*)d_in[17];
    const float* Wm0  = (const float*)d_in[18];
    const float* bm0  = (const float*)d_in[19];
    const float* Wm1  = (const float*)d_in[20];
    const float* bm1  = (const float*)d_in[21];
    const float* g_n0 = (const float*)d_in[22];
    const float* b_n0 = (const float*)d_in[23];
    const float* g_e0 = (const float*)d_in[24];
    const float* b_e0 = (const float*)d_in[25];
    const float* g_e1 = (const float*)d_in[26];
    const float* b_e1 = (const float*)d_in[27];
    const float* g_m  = (const float*)d_in[28];
    const float* b_m  = (const float*)d_in[29];
    const float* wsc  = (const float*)d_in[30];
    const int*   src  = (const int*)d_in[31];
    const int*   dst  = (const int*)d_in[32];

    const int N = in_sizes[0] / 96;
    const int E = in_sizes[1] / 32;

    float* ws    = (float*)d_ws;
    float* qkv   = ws;                                      // N*288 f32
    float* hp    = qkv + (size_t)N * 288;                   // N*96 f32
    unsigned short* agg16 = (unsigned short*)(hp + (size_t)N * 96);  // N*128 bf16
    unsigned short* exve5 = agg16 + (size_t)N * 128;        // E*160 bf16
    int*   eidx  = (int*)(exve5 + (size_t)E * 160);         // E
    int*   srcs  = eidx + E;                                // E
    int*   dsts  = srcs + E;                                // E
    int*   cnt   = dsts + E;                                // N
    int*   offv  = cnt + N;                                 // N
    int*   cur   = offv + N;                                // N
    float* tbuf  = ws;                                      // N*192, over dead qkv
    float* hout  = (float*)d_out;
    float* eoutp = (float*)d_out + (size_t)N * 96;

    hipMemsetAsync(cnt, 0, (size_t)N * sizeof(int), stream);

    const int mt = (N + 63) / 64;
    const int et = (E + 255) / 256;

    // CSR bucketing
    count_kernel<<<et, 256, 0, stream>>>(dst, cnt, E);
    scan_kernel<<<1, 1024, 0, stream>>>(cnt, offv, cur, N);
    scatter_kernel<<<et, 256, 0, stream>>>(dst, src, cur, eidx, srcs, dsts, E);

    // qkv = LN(feat) @ [Wq|Wk|Wv]  (LN fused)
    mgemm_kernel<1,1,0,0,0><<<dim3(mt, 3), 256, 0, stream>>>(
        feat, 96, Wq, Wk, Wv, 96, bq, bk, bv, g_n0, b_n0,
        nullptr, nullptr, qkv, 288, nullptr, N, 96);

    // fused edge tile pass (CSR order; writes exve5 + e-out)
    edge_tile_kernel<<<(E + 63) / 64, 256, 0, stream>>>(edge, qkv, eidx, srcs, dsts,
                                             We, be, Wb, bb, Wf0, bf0, Wf1, bf1,
                                             g_e0, b_e0, g_e1, b_e1,
                                             exve5, eoutp, E);

    // gather: streaming segmented sum -> agg16[N,128]
    gather_kernel<<<(N + 3) / 4, 256, 0, stream>>>(exve5, offv, cnt, agg16, N);

    // h_pre = feat*(1+w) + agg @ Wvv + bvv   (bf16 A)
    mgemm_kernel<0,0,1,0,1><<<dim3(mt, 1), 256, 0, stream>>>(
        agg16, 128, Wvv, Wvv, Wvv, 96, bvv, bvv, bvv, nullptr, nullptr,
        feat, wsc, hp, 96, nullptr, N, 128);
    // t = relu(LN(hp) @ Wm0 + bm0)   (LN fused)
    mgemm_kernel<0,1,0,1,0><<<dim3(mt, 2), 256, 0, stream>>>(
        hp, 96, Wm0, Wm0, Wm0, 192, bm0, bm0, bm0, g_m, b_m,
        nullptr, nullptr, tbuf, 192, nullptr, N, 96);
    // h_out = hp + t @ Wm1 + bm1
    mgemm_kernel<0,0,0,0,1><<<dim3(mt, 1), 256, 0, stream>>>(
        tbuf, 192, Wm1, Wm1, Wm1, 96, bm1, bm1, bm1, nullptr, nullptr,
        hp, nullptr, hout, 96, nullptr, N, 192);
}

// Round 15
// 915.098 us; speedup vs baseline: 1.2169x; 1.2169x over previous
//
#include <hip/hip_runtime.h>
#include <cstdint>
#include <cstddef>

// ---------------------------------------------------------------------------
// EGT layer.  N nodes (DIM=96, H=32, HD=3), E edges.
// edge_tile_kernel: 64 CSR-ordered slots per block (q[dst] L1-hot), qk
// in-kernel, MFMA bf16 GEMMs, exve16 written contiguously at slot.
// gather: contiguous exve16 + random v16 (L3-resident).
// mgemm: MFMA node GEMM with fused LN / bf16-A modes.
// ---------------------------------------------------------------------------

typedef short  s16x8 __attribute__((ext_vector_type(8)));
typedef short  s16x4 __attribute__((ext_vector_type(4)));
typedef float  f32x4 __attribute__((ext_vector_type(4)));

__device__ __forceinline__ unsigned short f2b(float x) {
    union { float f; unsigned u; } v; v.f = x;
    unsigned r = v.u + 0x7FFF + ((v.u >> 16) & 1);   // RNE
    return (unsigned short)(r >> 16);
}
__device__ __forceinline__ float b2f(unsigned short u) {
    union { unsigned u; float f; } v; v.u = ((unsigned)u) << 16; return v.f;
}

// ---------------- MFMA node GEMM ----------------
template<int MULTI, int LNA, int A16, int RELU, int RES>
__global__ __launch_bounds__(256) void mgemm_kernel(
    const void* __restrict__ Av, int lda,
    const float* __restrict__ B0, const float* __restrict__ B1,
    const float* __restrict__ B2, int ldb,
    const float* __restrict__ bias0, const float* __restrict__ bias1,
    const float* __restrict__ bias2,
    const float* __restrict__ lng, const float* __restrict__ lnbv,
    const float* __restrict__ resid, const float* __restrict__ wptr,
    float* __restrict__ C, int ldc, unsigned short* __restrict__ C16,
    int M, int K)
{
    __shared__ unsigned short sAL[64 * 200];
    __shared__ unsigned short sB[96 * 40];

    const int tid = threadIdx.x;
    const int m0 = blockIdx.x * 64;
    const int y  = blockIdx.y;
    const float* B = MULTI ? (y == 0 ? B0 : (y == 1 ? B1 : B2)) : B0;
    const int nbB = MULTI ? 0 : y * 96;
    const int nbC = y * 96;
    const int w = tid >> 6, l = tid & 63, fr = l & 15, kg = l >> 4;
    const int KP = K + 8;

    if (LNA) {
        const float* Af = (const float*)Av;
        const int row = 16 * w + fr;
        const int grow = m0 + row;
        float x[24];
        if (grow < M) {
            #pragma unroll
            for (int t = 0; t < 6; t++)
                *(float4*)&x[t * 4] = *(const float4*)(Af + (size_t)grow * lda + 24 * kg + t * 4);
        } else {
            #pragma unroll
            for (int t = 0; t < 24; t++) x[t] = 0.f;
        }
        float s = 0.f;
        #pragma unroll
        for (int t = 0; t < 24; t++) s += x[t];
        s += __shfl_xor(s, 16, 64); s += __shfl_xor(s, 32, 64);
        float mu = s * (1.f / 96.f);
        float v2 = 0.f;
        #pragma unroll
        for (int t = 0; t < 24; t++) { float d = x[t] - mu; v2 += d * d; }
        v2 += __shfl_xor(v2, 16, 64); v2 += __shfl_xor(v2, 32, 64);
        float rs = rsqrtf(v2 * (1.f / 96.f) + 1e-5f);
        #pragma unroll
        for (int t3 = 0; t3 < 3; t3++) {
            s16x8 yv;
            #pragma unroll
            for (int u = 0; u < 8; u++) {
                int cidx = 24 * kg + t3 * 8 + u;
                yv[u] = (short)f2b((x[t3 * 8 + u] - mu) * rs * lng[cidx] + lnbv[cidx]);
            }
            *(s16x8*)&sAL[row * KP + 24 * kg + t3 * 8] = yv;
        }
    } else {
        const int nseg = K >> 3;
        for (int idx = tid; idx < 64 * nseg; idx += 256) {
            int row = idx / nseg, k8 = (idx - row * nseg) * 8;
            int grow = m0 + row;
            s16x8 a8 = (s16x8){0, 0, 0, 0, 0, 0, 0, 0};
            if (grow < M) {
                if (A16) {
                    a8 = *(const s16x8*)((const unsigned short*)Av + (size_t)grow * lda + k8);
                } else {
                    const float* Af = (const float*)Av;
                    float4 v0 = *(const float4*)(Af + (size_t)grow * lda + k8);
                    float4 v1 = *(const float4*)(Af + (size_t)grow * lda + k8 + 4);
                    a8[0] = (short)f2b(v0.x); a8[1] = (short)f2b(v0.y);
                    a8[2] = (short)f2b(v0.z); a8[3] = (short)f2b(v0.w);
                    a8[4] = (short)f2b(v1.x); a8[5] = (short)f2b(v1.y);
                    a8[6] = (short)f2b(v1.z); a8[7] = (short)f2b(v1.w);
                }
            }
            *(s16x8*)&sAL[row * KP + k8] = a8;
        }
    }

    f32x4 acc[6];
    #pragma unroll
    for (int i = 0; i < 6; i++) acc[i] = (f32x4){0.f, 0.f, 0.f, 0.f};

    for (int kc = 0; kc < K; kc += 32) {
        #pragma unroll
        for (int r = 0; r < 3; r++) {
            int idx = tid + 256 * r;
            int k = idx / 24, n4 = (idx - k * 24) * 4;
            float4 v = *(const float4*)(B + (size_t)(kc + k) * ldb + nbB + n4);
            sB[(n4 + 0) * 40 + k] = f2b(v.x);
            sB[(n4 + 1) * 40 + k] = f2b(v.y);
            sB[(n4 + 2) * 40 + k] = f2b(v.z);
            sB[(n4 + 3) * 40 + k] = f2b(v.w);
        }
        __syncthreads();
        {
            s16x8 a = *(s16x8*)&sAL[(16 * w + fr) * KP + kc + kg * 8];
            #pragma unroll
            for (int nt = 0; nt < 6; nt++) {
                s16x8 b = *(s16x8*)&sB[(16 * nt + fr) * 40 + kg * 8];
                acc[nt] = __builtin_amdgcn_mfma_f32_16x16x32_bf16(a, b, acc[nt], 0, 0, 0);
            }
        }
        __syncthreads();
    }

    float scale = 1.f;
    if (RES) scale = wptr ? (1.f + wptr[0]) : 1.f;
    const float* biasp = MULTI ? (y == 0 ? bias0 : (y == 1 ? bias1 : bias2)) : bias0;
    const int bbase = MULTI ? 0 : nbB;

    #pragma unroll
    for (int nt = 0; nt < 6; nt++) {
        int cl = nt * 16 + fr;
        float bv = biasp[bbase + cl];
        int gcol = nbC + cl;
        #pragma unroll
        for (int r = 0; r < 4; r++) {
            int row = m0 + 16 * w + 4 * kg + r;
            if (row >= M) continue;
            float v = acc[nt][r] + bv;
            if (RELU) v = fmaxf(v, 0.f);
            if (RES) v += scale * resid[(size_t)row * ldc + gcol];
            C[(size_t)row * ldc + gcol] = v;
            if (MULTI && C16 != nullptr && y == 2)
                C16[(size_t)row * 96 + cl] = f2b(v);
        }
    }
}

// ---------------- CSR bucketing ----------------
__global__ __launch_bounds__(256) void count_kernel(
    const int* __restrict__ dst, int* __restrict__ cnt, int E)
{
    int i = blockIdx.x * 256 + threadIdx.x;
    if (i < E) atomicAdd(&cnt[dst[i]], 1);
}

__global__ __launch_bounds__(1024) void scan_kernel(
    const int* __restrict__ cnt, int* __restrict__ off, int* __restrict__ cur, int N)
{
    __shared__ int s[1024];
    const int tid = threadIdx.x;
    const int chunk = (N + 1023) >> 10;
    const int lo = tid * chunk;
    const int hi = min(lo + chunk, N);
    int sum = 0;
    for (int i = lo; i < hi; i++) sum += cnt[i];
    s[tid] = sum;
    __syncthreads();
    for (int d = 1; d < 1024; d <<= 1) {
        int v = (tid >= d) ? s[tid - d] : 0;
        __syncthreads();
        s[tid] += v;
        __syncthreads();
    }
    int base = (tid == 0) ? 0 : s[tid - 1];
    for (int i = lo; i < hi; i++) {
        off[i] = base; cur[i] = base;
        base += cnt[i];
    }
}

// scatter: slot arrays eidx/srcs/dsts (CSR order)
__global__ __launch_bounds__(256) void scatter_kernel(
    const int* __restrict__ dst, const int* __restrict__ src,
    int* __restrict__ cur, int* __restrict__ eidx,
    int* __restrict__ srcs, int* __restrict__ dsts, int E)
{
    int i = blockIdx.x * 256 + threadIdx.x;
    if (i < E) {
        int p = atomicAdd(&cur[dst[i]], 1);
        eidx[p] = i;
        srcs[p] = src[i];
        dsts[p] = dst[i];
    }
}

// ---------------- edge tile kernel: 64 CSR slots per block ------------------
// exve16 (bf16) layout: [slot][64] = {ex[0..32), ve[32..64)}
__global__ __launch_bounds__(256, 4) void edge_tile_kernel(
    const float* __restrict__ edge, const float* __restrict__ qkv,
    const int* __restrict__ eidx, const int* __restrict__ srcs,
    const int* __restrict__ dsts,
    const float* __restrict__ We, const float* __restrict__ be,
    const float* __restrict__ Wb, const float* __restrict__ bb,
    const float* __restrict__ Wf0, const float* __restrict__ bf0,
    const float* __restrict__ Wf1, const float* __restrict__ bf1,
    const float* __restrict__ ge0, const float* __restrict__ be0,
    const float* __restrict__ ge1, const float* __restrict__ be1,
    unsigned short* __restrict__ exve16, float* __restrict__ eout, int E)
{
    __shared__ float          sEV[64 * 36];   // ev -> er
    __shared__ unsigned short sQK[64 * 44];   // qk bf16 (pad 44: banks 0/24/16/8)
    __shared__ unsigned short sA [64 * 40];   // ew/en bf16
    __shared__ unsigned short sB [64 * 40];   // Wb|We then Wf0
    __shared__ unsigned short sB2[32 * 72];   // Wf1^T
    __shared__ unsigned short sX [64 * 76];   // ex|ve then F (pad 76)
    // total 39,424 B -> 4 blocks/CU

    const int tid = threadIdx.x;
    const long long e0 = (long long)blockIdx.x * 64;
    const int w  = tid >> 6;
    const int l  = tid & 63;
    const int fr = l & 15;
    const int kg = l >> 4;

    // ---- S1a: fused score in CSR order (q[dst] L1-hot) ----
    {
        const int row = tid >> 2;
        const int j   = tid & 3;
        long long s = e0 + row;
        float q[24], k[24];
        if (s < E) {
            int dn = dsts[s], sn = srcs[s];
            const float* qp = qkv + (size_t)dn * 288 + 24 * j;
            const float* kp = qkv + (size_t)sn * 288 + 96 + 24 * j;
            #pragma unroll
            for (int t = 0; t < 6; t++) {
                *(float4*)&q[t * 4] = *(const float4*)(qp + t * 4);
                *(float4*)&k[t * 4] = *(const float4*)(kp + t * 4);
            }
        } else {
            #pragma unroll
            for (int t = 0; t < 24; t++) { q[t] = 0.f; k[t] = 0.f; }
        }
        s16x8 qkb;
        #pragma unroll
        for (int t = 0; t < 8; t++) {
            float d = k[3*t]*q[3*t] + k[3*t+1]*q[3*t+1] + k[3*t+2]*q[3*t+2];
            qkb[t] = (short)f2b(0.5f * d);
        }
        *(s16x8*)&sQK[row * 44 + 8 * j] = qkb;
    }

    // ---- S1b: stage ev (via eidx), Wb|We^T (bf16), Wf1^T (bf16) ----
    #pragma unroll
    for (int rr = 0; rr < 2; rr++) {
        int idx = tid + 256 * rr;
        int row = idx >> 3, c4 = (idx & 7) * 4;
        long long s = e0 + row;
        float4 v = make_float4(0.f, 0.f, 0.f, 0.f);
        if (s < E) {
            int ge = eidx[s];
            v = *(const float4*)(edge + (size_t)ge * 32 + c4);
        }
        *(float4*)&sEV[row * 36 + c4] = v;
    }
    {
        int k = tid >> 3, c4 = (tid & 7) * 4;
        float4 vb = *(const float4*)(Wb + k * 32 + c4);
        float4 ve = *(const float4*)(We + k * 32 + c4);
        sB[(c4 + 0) * 40 + k] = f2b(vb.x); sB[(c4 + 1) * 40 + k] = f2b(vb.y);
        sB[(c4 + 2) * 40 + k] = f2b(vb.z); sB[(c4 + 3) * 40 + k] = f2b(vb.w);
        sB[(32 + c4 + 0) * 40 + k] = f2b(ve.x); sB[(32 + c4 + 1) * 40 + k] = f2b(ve.y);
        sB[(32 + c4 + 2) * 40 + k] = f2b(ve.z); sB[(32 + c4 + 3) * 40 + k] = f2b(ve.w);
    }
    #pragma unroll
    for (int rr = 0; rr < 2; rr++) {
        int idx = tid + 256 * rr;
        int k = idx >> 3, c4 = (idx & 7) * 4;
        float4 v = *(const float4*)(Wf1 + k * 32 + c4);
        sB2[(c4 + 0) * 72 + k] = f2b(v.x); sB2[(c4 + 1) * 72 + k] = f2b(v.y);
        sB2[(c4 + 2) * 72 + k] = f2b(v.z); sB2[(c4 + 3) * 72 + k] = f2b(v.w);
    }
    __syncthreads();

    // ---- S2: LN1 -> ew rows (bf16) in sA ----
    {
        const int row = 16 * w + (tid & 15);
        const int q = (tid & 63) >> 4;
        float x[8];
        *(float4*)&x[0] = *(float4*)&sEV[row * 36 + 8 * q];
        *(float4*)&x[4] = *(float4*)&sEV[row * 36 + 8 * q + 4];
        float s = x[0] + x[1] + x[2] + x[3] + x[4] + x[5] + x[6] + x[7];
        s += __shfl_xor(s, 16, 64); s += __shfl_xor(s, 32, 64);
        float mu = s * (1.f / 32.f);
        float v2 = 0.f;
        #pragma unroll
        for (int i = 0; i < 8; i++) { float d = x[i] - mu; v2 += d * d; }
        v2 += __shfl_xor(v2, 16, 64); v2 += __shfl_xor(v2, 32, 64);
        float rs = rsqrtf(v2 * (1.f / 32.f) + 1e-5f);
        float4 g1 = *(const float4*)(ge0 + 8 * q), g2 = *(const float4*)(ge0 + 8 * q + 4);
        float4 b1 = *(const float4*)(be0 + 8 * q), b2 = *(const float4*)(be0 + 8 * q + 4);
        float gg[8] = {g1.x, g1.y, g1.z, g1.w, g2.x, g2.y, g2.z, g2.w};
        float bs[8] = {b1.x, b1.y, b1.z, b1.w, b2.x, b2.y, b2.z, b2.w};
        s16x8 y;
        #pragma unroll
        for (int i = 0; i < 8; i++)
            y[i] = (short)f2b((x[i] - mu) * rs * gg[i] + bs[i]);
        *(s16x8*)&sA[row * 40 + 8 * q] = y;
    }
    __syncthreads();

    // ---- S3: GEMM1 (MFMA)  [64][64 = sc|veh] = ew @ [Wb|We] ----
    f32x4 acc[4];
    {
        s16x8 a = *(s16x8*)&sA[(16 * w + fr) * 40 + kg * 8];
        #pragma unroll
        for (int nt = 0; nt < 4; nt++) {
            s16x8 b = *(s16x8*)&sB[(16 * nt + fr) * 40 + kg * 8];
            f32x4 z = {0.f, 0.f, 0.f, 0.f};
            acc[nt] = __builtin_amdgcn_mfma_f32_16x16x32_bf16(a, b, z, 0, 0, 0);
        }
    }
    __syncthreads();

    // ---- S4: epilogue1 (ex|ve -> sX; er -> sEV) + restage Wf0 -> sB ----
    #pragma unroll
    for (int nt = 0; nt < 2; nt++) {
        int col = nt * 16 + fr;
        float bbv = bb[col];
        #pragma unroll
        for (int r = 0; r < 4; r++) {
            int row = 16 * w + 4 * kg + r;
            float sc = acc[nt][r] + b2f(sQK[row * 44 + col]) + bbv;
            sX[row * 76 + col] = f2b(__expf(sc));
            float er = sc + sEV[row * 36 + col];
            sEV[row * 36 + col] = er;
        }
    }
    #pragma unroll
    for (int nt = 2; nt < 4; nt++) {
        int col = (nt - 2) * 16 + fr;
        float bev = be[col];
        #pragma unroll
        for (int r = 0; r < 4; r++) {
            int row = 16 * w + 4 * kg + r;
            sX[row * 76 + 32 + col] = f2b(acc[nt][r] + bev);
        }
    }
    #pragma unroll
    for (int rr = 0; rr < 2; rr++) {
        int idx = tid + 256 * rr;
        int k = idx >> 4, c4 = (idx & 15) * 4;
        float4 v = *(const float4*)(Wf0 + k * 64 + c4);
        sB[(c4 + 0) * 40 + k] = f2b(v.x); sB[(c4 + 1) * 40 + k] = f2b(v.y);
        sB[(c4 + 2) * 40 + k] = f2b(v.z); sB[(c4 + 3) * 40 + k] = f2b(v.w);
    }
    __syncthreads();

    // ---- S5: copy sX -> exve16 contiguously at slot ; LN2 -> sA ----
    #pragma unroll
    for (int rr = 0; rr < 2; rr++) {
        int idx = tid + 256 * rr;
        int row = idx >> 3, c8 = (idx & 7) * 8;
        long long s = e0 + row;
        if (s < E)
            *(s16x8*)(exve16 + (size_t)s * 64 + c8) = *(s16x8*)&sX[row * 76 + c8];
    }
    {
        const int row = 16 * w + (tid & 15);
        const int q = (tid & 63) >> 4;
        float x[8];
        *(float4*)&x[0] = *(float4*)&sEV[row * 36 + 8 * q];
        *(float4*)&x[4] = *(float4*)&sEV[row * 36 + 8 * q + 4];
        float s = x[0] + x[1] + x[2] + x[3] + x[4] + x[5] + x[6] + x[7];
        s += __shfl_xor(s, 16, 64); s += __shfl_xor(s, 32, 64);
        float mu = s * (1.f / 32.f);
        float v2 = 0.f;
        #pragma unroll
        for (int i = 0; i < 8; i++) { float d = x[i] - mu; v2 += d * d; }
        v2 += __shfl_xor(v2, 16, 64); v2 += __shfl_xor(v2, 32, 64);
        float rs = rsqrtf(v2 * (1.f / 32.f) + 1e-5f);
        float4 g1 = *(const float4*)(ge1 + 8 * q), g2 = *(const float4*)(ge1 + 8 * q + 4);
        float4 b1 = *(const float4*)(be1 + 8 * q), b2 = *(const float4*)(be1 + 8 * q + 4);
        float gg[8] = {g1.x, g1.y, g1.z, g1.w, g2.x, g2.y, g2.z, g2.w};
        float bs[8] = {b1.x, b1.y, b1.z, b1.w, b2.x, b2.y, b2.z, b2.w};
        s16x8 y;
        #pragma unroll
        for (int i = 0; i < 8; i++)
            y[i] = (short)f2b((x[i] - mu) * rs * gg[i] + bs[i]);
        *(s16x8*)&sA[row * 40 + 8 * q] = y;
    }
    __syncthreads();

    // ---- S6: GEMM2 (MFMA)  F[64][64] = relu(en @ Wf0 + bf0) -> sX ----
    {
        s16x8 a = *(s16x8*)&sA[(16 * w + fr) * 40 + kg * 8];
        #pragma unroll
        for (int nt = 0; nt < 4; nt++) {
            s16x8 b = *(s16x8*)&sB[(16 * nt + fr) * 40 + kg * 8];
            f32x4 z = {0.f, 0.f, 0.f, 0.f};
            f32x4 a2 = __builtin_amdgcn_mfma_f32_16x16x32_bf16(a, b, z, 0, 0, 0);
            int col = nt * 16 + fr;
            float b0v = bf0[col];
            #pragma unroll
            for (int r = 0; r < 4; r++) {
                int row = 16 * w + 4 * kg + r;
                sX[row * 76 + col] = f2b(fmaxf(a2[r] + b0v, 0.f));
            }
        }
    }
    __syncthreads();

    // ---- S7: GEMM3 (MFMA)  out[64][32] = F @ Wf1 + er + bf1 -> sEV ----
    {
        s16x8 a0 = *(s16x8*)&sX[(16 * w + fr) * 76 + kg * 8];
        s16x8 a1 = *(s16x8*)&sX[(16 * w + fr) * 76 + 32 + kg * 8];
        #pragma unroll
        for (int nt = 0; nt < 2; nt++) {
            s16x8 b0 = *(s16x8*)&sB2[(16 * nt + fr) * 72 + kg * 8];
            s16x8 b1 = *(s16x8*)&sB2[(16 * nt + fr) * 72 + 32 + kg * 8];
            f32x4 z = {0.f, 0.f, 0.f, 0.f};
            f32x4 t = __builtin_amdgcn_mfma_f32_16x16x32_bf16(a0, b0, z, 0, 0, 0);
            t = __builtin_amdgcn_mfma_f32_16x16x32_bf16(a1, b1, t, 0, 0, 0);
            int col = nt * 16 + fr;
            float bf1v = bf1[col];
            #pragma unroll
            for (int r = 0; r < 4; r++) {
                int row = 16 * w + 4 * kg + r;
                float out = t[r] + sEV[row * 36 + col] + bf1v;
                sEV[row * 36 + col] = out;
            }
        }
    }
    __syncthreads();

    // ---- S8: copy sEV[:, 0..32) -> eout[eidx[s]] ----
    #pragma unroll
    for (int rr = 0; rr < 2; rr++) {
        int idx = tid + 256 * rr;
        int row = idx >> 3, c4 = (idx & 7) * 4;
        long long s = e0 + row;
        if (s < E) {
            int ge = eidx[s];
            *(float4*)(eout + (size_t)ge * 32 + c4) = *(float4*)&sEV[row * 36 + c4];
        }
    }
}

// ---------------- gather: wave/node, 2 edges in flight per half ------------
__global__ __launch_bounds__(256) void gather_kernel(
    const unsigned short* __restrict__ exve16, const unsigned short* __restrict__ v16,
    const int* __restrict__ srcs, const int* __restrict__ off,
    const int* __restrict__ cnt, unsigned short* __restrict__ agg16, int N)
{
    __shared__ unsigned short sV16[4][2][2][96];
    __shared__ unsigned short sE16[4][2][2][64];
    const int wave = threadIdx.x >> 6;
    const int lane = threadIdx.x & 63;
    const int head = lane & 31;
    const int half = lane >> 5;
    int n = blockIdx.x * 4 + wave;
    if (n >= N) return;
    const int o = off[n], d = cnt[n];
    float a0 = 0.f, a1 = 0.f, a2 = 0.f, a3 = 0.f, den = 0.f;
    for (int i = half; i < d; i += 4) {
        const int i2 = i + 2;
        {
            int sn = srcs[o + i];
            const unsigned short* vr = v16 + (size_t)sn * 96;
            const unsigned short* er = exve16 + (size_t)(o + i) * 64;
            if (head < 12)
                *(s16x8*)&sV16[wave][half][0][head * 8] = *(const s16x8*)(vr + head * 8);
            else if (head >= 24)
                *(s16x8*)&sE16[wave][half][0][(head - 24) * 8] = *(const s16x8*)(er + (head - 24) * 8);
        }
        if (i2 < d) {
            int sn = srcs[o + i2];
            const unsigned short* vr = v16 + (size_t)sn * 96;
            const unsigned short* er = exve16 + (size_t)(o + i2) * 64;
            if (head < 12)
                *(s16x8*)&sV16[wave][half][1][head * 8] = *(const s16x8*)(vr + head * 8);
            else if (head >= 24)
                *(s16x8*)&sE16[wave][half][1][(head - 24) * 8] = *(const s16x8*)(er + (head - 24) * 8);
        }
        __builtin_amdgcn_wave_barrier();
        {
            float ex = b2f(sE16[wave][half][0][head]);
            float vv = b2f(sE16[wave][half][0][32 + head]);
            a0 += ex * b2f(sV16[wave][half][0][head * 3]);
            a1 += ex * b2f(sV16[wave][half][0][head * 3 + 1]);
            a2 += ex * b2f(sV16[wave][half][0][head * 3 + 2]);
            a3 += ex * vv;
            den += ex;
        }
        if (i2 < d) {
            float ex = b2f(sE16[wave][half][1][head]);
            float vv = b2f(sE16[wave][half][1][32 + head]);
            a0 += ex * b2f(sV16[wave][half][1][head * 3]);
            a1 += ex * b2f(sV16[wave][half][1][head * 3 + 1]);
            a2 += ex * b2f(sV16[wave][half][1][head * 3 + 2]);
            a3 += ex * vv;
            den += ex;
        }
        __builtin_amdgcn_wave_barrier();
    }
    a0 += __shfl_xor(a0, 32, 64);
    a1 += __shfl_xor(a1, 32, 64);
    a2 += __shfl_xor(a2, 32, 64);
    a3 += __shfl_xor(a3, 32, 64);
    den += __shfl_xor(den, 32, 64);
    if (half == 0) {
        float sc = (d > 0) ? 1.f / den : 0.f;
        s16x4 ov;
        ov[0] = (short)f2b(a0 * sc);
        ov[1] = (short)f2b(a1 * sc);
        ov[2] = (short)f2b(a2 * sc);
        ov[3] = (short)f2b(a3 * sc);
        *(s16x4*)(agg16 + (size_t)n * 128 + head * 4) = ov;
    }
}

// ---------------------------------------------------------------------------
extern "C" void kernel_launch(void* const* d_in, const int* in_sizes, int n_in,
                              void* d_out, int out_size, void* d_ws, size_t ws_size,
                              hipStream_t stream)
{
    (void)n_in; (void)out_size; (void)ws_size;
    const float* feat = (const float*)d_in[0];
    const float* edge = (const float*)d_in[1];
    const float* Wq   = (const float*)d_in[2];
    const float* bq   = (const float*)d_in[3];
    const float* Wk   = (const float*)d_in[4];
    const float* bk   = (const float*)d_in[5];
    const float* Wv   = (const float*)d_in[6];
    const float* bv   = (const float*)d_in[7];
    const float* We   = (const float*)d_in[8];
    const float* be   = (const float*)d_in[9];
    const float* Wb   = (const float*)d_in[10];
    const float* bb   = (const float*)d_in[11];
    const float* Wvv  = (const float*)d_in[12];
    const float* bvv  = (const float*)d_in[13];
    const float* Wf0  = (const float*)d_in[14];
    const float* bf0  = (const float*)d_in[15];
    const float* Wf1  = (const float*)d_in[16];
    const float* bf1  = (const float*)d_in[17];
    const float* Wm0  = (const float*)d_in[18];
    const float* bm0  = (const float*)d_in[19];
    const float* Wm1  = (const float*)d_in[20];
    const float* bm1  = (const float*)d_in[21];
    const float* g_n0 = (const float*)d_in[22];
    const float* b_n0 = (const float*)d_in[23];
    const float* g_e0 = (const float*)d_in[24];
    const float* b_e0 = (const float*)d_in[25];
    const float* g_e1 = (const float*)d_in[26];
    const float* b_e1 = (const float*)d_in[27];
    const float* g_m  = (const float*)d_in[28];
    const float* b_m  = (const float*)d_in[29];
    const float* wsc  = (const float*)d_in[30];
    const int*   src  = (const int*)d_in[31];
    const int*   dst  = (const int*)d_in[32];

    const int N = in_sizes[0] / 96;
    const int E = in_sizes[1] / 32;

    float* ws    = (float*)d_ws;
    float* qkv   = ws;                                      // N*288 f32
    float* hp    = qkv + (size_t)N * 288;                   // N*96 f32
    unsigned short* agg16 = (unsigned short*)(hp + (size_t)N * 96);  // N*128 bf16
    unsigned short* v16   = agg16 + (size_t)N * 128;        // N*96 bf16
    unsigned short* exve16 = v16 + (size_t)N * 96;          // E*64 bf16
    int*   eidx  = (int*)(exve16 + (size_t)E * 64);         // E
    int*   srcs  = eidx + E;                                // E
    int*   dsts  = srcs + E;                                // E
    int*   cnt   = dsts + E;                                // N
    int*   offv  = cnt + N;                                 // N
    int*   cur   = offv + N;                                // N
    float* tbuf  = ws;                                      // N*192, over dead qkv
    float* hout  = (float*)d_out;
    float* eoutp = (float*)d_out + (size_t)N * 96;

    hipMemsetAsync(cnt, 0, (size_t)N * sizeof(int), stream);

    const int mt = (N + 63) / 64;
    const int et = (E + 255) / 256;

    // CSR bucketing
    count_kernel<<<et, 256, 0, stream>>>(dst, cnt, E);
    scan_kernel<<<1, 1024, 0, stream>>>(cnt, offv, cur, N);
    scatter_kernel<<<et, 256, 0, stream>>>(dst, src, cur, eidx, srcs, dsts, E);

    // qkv = LN(feat) @ [Wq|Wk|Wv]  (LN fused; y==2 also emits bf16 v16)
    mgemm_kernel<1,1,0,0,0><<<dim3(mt, 3), 256, 0, stream>>>(
        feat, 96, Wq, Wk, Wv, 96, bq, bk, bv, g_n0, b_n0,
        nullptr, nullptr, qkv, 288, v16, N, 96);

    // fused edge tile pass (CSR slot order)
    edge_tile_kernel<<<(E + 63) / 64, 256, 0, stream>>>(edge, qkv, eidx, srcs, dsts,
                                             We, be, Wb, bb, Wf0, bf0, Wf1, bf1,
                                             g_e0, b_e0, g_e1, b_e1,
                                             exve16, eoutp, E);

    // gather per node -> normalized agg16[N,128] (bf16)
    gather_kernel<<<(N + 3) / 4, 256, 0, stream>>>(exve16, v16, srcs, offv, cnt, agg16, N);

    // h_pre = feat*(1+w) + agg @ Wvv + bvv   (bf16 A)
    mgemm_kernel<0,0,1,0,1><<<dim3(mt, 1), 256, 0, stream>>>(
        agg16, 128, Wvv, Wvv, Wvv, 96, bvv, bvv, bvv, nullptr, nullptr,
        feat, wsc, hp, 96, nullptr, N, 128);
    // t = relu(LN(hp) @ Wm0 + bm0)   (LN fused)
    mgemm_kernel<0,1,0,1,0><<<dim3(mt, 2), 256, 0, stream>>>(
        hp, 96, Wm0, Wm0, Wm0, 192, bm0, bm0, bm0, g_m, b_m,
        nullptr, nullptr, tbuf, 192, nullptr, N, 96);
    // h_out = hp + t @ Wm1 + bm1
    mgemm_kernel<0,0,0,0,1><<<dim3(mt, 1), 256, 0, stream>>>(
        tbuf, 192, Wm1, Wm1, Wm1, 96, bm1, bm1, bm1, nullptr, nullptr,
        hp, nullptr, hout, 96, nullptr, N, 192);
}

// Round 16
// 826.809 us; speedup vs baseline: 1.3469x; 1.1068x over previous
//
#include <hip/hip_runtime.h>
#include <cstdint>
#include <cstddef>

// ---------------------------------------------------------------------------
// EGT layer.  N nodes (DIM=96, H=32, HD=3), E edges.
// qkv kept ONLY as bf16 (qkv16[N][288], ~L2-resident) -- MULTI mgemm writes it.
// Bucketing: count emits rank[e]; scatter is atomic-free (off[dst]+rank).
// edge_tile_kernel: 64 CSR slots per block, q/k from qkv16, MFMA bf16 GEMMs.
// gather: contiguous exve16 + v rows from qkv16.
// ---------------------------------------------------------------------------

typedef short  s16x8 __attribute__((ext_vector_type(8)));
typedef short  s16x4 __attribute__((ext_vector_type(4)));
typedef float  f32x4 __attribute__((ext_vector_type(4)));

__device__ __forceinline__ unsigned short f2b(float x) {
    union { float f; unsigned u; } v; v.f = x;
    unsigned r = v.u + 0x7FFF + ((v.u >> 16) & 1);   // RNE
    return (unsigned short)(r >> 16);
}
__device__ __forceinline__ float b2f(unsigned short u) {
    union { unsigned u; float f; } v; v.u = ((unsigned)u) << 16; return v.f;
}

// ---------------- MFMA node GEMM ----------------
// MULTI: y selects B0/B1/B2 (q|k|v); writes ONLY bf16 C16[N][288] slice.
template<int MULTI, int LNA, int A16, int RELU, int RES>
__global__ __launch_bounds__(256) void mgemm_kernel(
    const void* __restrict__ Av, int lda,
    const float* __restrict__ B0, const float* __restrict__ B1,
    const float* __restrict__ B2, int ldb,
    const float* __restrict__ bias0, const float* __restrict__ bias1,
    const float* __restrict__ bias2,
    const float* __restrict__ lng, const float* __restrict__ lnbv,
    const float* __restrict__ resid, const float* __restrict__ wptr,
    float* __restrict__ C, int ldc, unsigned short* __restrict__ C16,
    int M, int K)
{
    __shared__ unsigned short sAL[64 * 200];
    __shared__ unsigned short sB[96 * 40];

    const int tid = threadIdx.x;
    const int m0 = blockIdx.x * 64;
    const int y  = blockIdx.y;
    const float* B = MULTI ? (y == 0 ? B0 : (y == 1 ? B1 : B2)) : B0;
    const int nbB = MULTI ? 0 : y * 96;
    const int nbC = y * 96;
    const int w = tid >> 6, l = tid & 63, fr = l & 15, kg = l >> 4;
    const int KP = K + 8;

    if (LNA) {
        const float* Af = (const float*)Av;
        const int row = 16 * w + fr;
        const int grow = m0 + row;
        float x[24];
        if (grow < M) {
            #pragma unroll
            for (int t = 0; t < 6; t++)
                *(float4*)&x[t * 4] = *(const float4*)(Af + (size_t)grow * lda + 24 * kg + t * 4);
        } else {
            #pragma unroll
            for (int t = 0; t < 24; t++) x[t] = 0.f;
        }
        float s = 0.f;
        #pragma unroll
        for (int t = 0; t < 24; t++) s += x[t];
        s += __shfl_xor(s, 16, 64); s += __shfl_xor(s, 32, 64);
        float mu = s * (1.f / 96.f);
        float v2 = 0.f;
        #pragma unroll
        for (int t = 0; t < 24; t++) { float d = x[t] - mu; v2 += d * d; }
        v2 += __shfl_xor(v2, 16, 64); v2 += __shfl_xor(v2, 32, 64);
        float rs = rsqrtf(v2 * (1.f / 96.f) + 1e-5f);
        #pragma unroll
        for (int t3 = 0; t3 < 3; t3++) {
            s16x8 yv;
            #pragma unroll
            for (int u = 0; u < 8; u++) {
                int cidx = 24 * kg + t3 * 8 + u;
                yv[u] = (short)f2b((x[t3 * 8 + u] - mu) * rs * lng[cidx] + lnbv[cidx]);
            }
            *(s16x8*)&sAL[row * KP + 24 * kg + t3 * 8] = yv;
        }
    } else {
        const int nseg = K >> 3;
        for (int idx = tid; idx < 64 * nseg; idx += 256) {
            int row = idx / nseg, k8 = (idx - row * nseg) * 8;
            int grow = m0 + row;
            s16x8 a8 = (s16x8){0, 0, 0, 0, 0, 0, 0, 0};
            if (grow < M) {
                if (A16) {
                    a8 = *(const s16x8*)((const unsigned short*)Av + (size_t)grow * lda + k8);
                } else {
                    const float* Af = (const float*)Av;
                    float4 v0 = *(const float4*)(Af + (size_t)grow * lda + k8);
                    float4 v1 = *(const float4*)(Af + (size_t)grow * lda + k8 + 4);
                    a8[0] = (short)f2b(v0.x); a8[1] = (short)f2b(v0.y);
                    a8[2] = (short)f2b(v0.z); a8[3] = (short)f2b(v0.w);
                    a8[4] = (short)f2b(v1.x); a8[5] = (short)f2b(v1.y);
                    a8[6] = (short)f2b(v1.z); a8[7] = (short)f2b(v1.w);
                }
            }
            *(s16x8*)&sAL[row * KP + k8] = a8;
        }
    }

    f32x4 acc[6];
    #pragma unroll
    for (int i = 0; i < 6; i++) acc[i] = (f32x4){0.f, 0.f, 0.f, 0.f};

    for (int kc = 0; kc < K; kc += 32) {
        #pragma unroll
        for (int r = 0; r < 3; r++) {
            int idx = tid + 256 * r;
            int k = idx / 24, n4 = (idx - k * 24) * 4;
            float4 v = *(const float4*)(B + (size_t)(kc + k) * ldb + nbB + n4);
            sB[(n4 + 0) * 40 + k] = f2b(v.x);
            sB[(n4 + 1) * 40 + k] = f2b(v.y);
            sB[(n4 + 2) * 40 + k] = f2b(v.z);
            sB[(n4 + 3) * 40 + k] = f2b(v.w);
        }
        __syncthreads();
        {
            s16x8 a = *(s16x8*)&sAL[(16 * w + fr) * KP + kc + kg * 8];
            #pragma unroll
            for (int nt = 0; nt < 6; nt++) {
                s16x8 b = *(s16x8*)&sB[(16 * nt + fr) * 40 + kg * 8];
                acc[nt] = __builtin_amdgcn_mfma_f32_16x16x32_bf16(a, b, acc[nt], 0, 0, 0);
            }
        }
        __syncthreads();
    }

    float scale = 1.f;
    if (RES) scale = wptr ? (1.f + wptr[0]) : 1.f;
    const float* biasp = MULTI ? (y == 0 ? bias0 : (y == 1 ? bias1 : bias2)) : bias0;
    const int bbase = MULTI ? 0 : nbB;

    #pragma unroll
    for (int nt = 0; nt < 6; nt++) {
        int cl = nt * 16 + fr;
        float bv = biasp[bbase + cl];
        int gcol = nbC + cl;
        #pragma unroll
        for (int r = 0; r < 4; r++) {
            int row = m0 + 16 * w + 4 * kg + r;
            if (row >= M) continue;
            float v = acc[nt][r] + bv;
            if (RELU) v = fmaxf(v, 0.f);
            if (MULTI) {
                C16[(size_t)row * 288 + gcol] = f2b(v);
            } else {
                if (RES) v += scale * resid[(size_t)row * ldc + gcol];
                C[(size_t)row * ldc + gcol] = v;
            }
        }
    }
}

// ---------------- CSR bucketing ----------------
// count: histogram + per-edge rank (atomic return value).
__global__ __launch_bounds__(256) void count_kernel(
    const int* __restrict__ dst, int* __restrict__ cnt,
    int* __restrict__ rank, int E)
{
    int i = blockIdx.x * 256 + threadIdx.x;
    if (i < E) rank[i] = atomicAdd(&cnt[dst[i]], 1);
}

__global__ __launch_bounds__(1024) void scan_kernel(
    const int* __restrict__ cnt, int* __restrict__ off, int N)
{
    __shared__ int s[1024];
    const int tid = threadIdx.x;
    const int chunk = (N + 1023) >> 10;
    const int lo = tid * chunk;
    const int hi = min(lo + chunk, N);
    int sum = 0;
    for (int i = lo; i < hi; i++) sum += cnt[i];
    s[tid] = sum;
    __syncthreads();
    for (int d = 1; d < 1024; d <<= 1) {
        int v = (tid >= d) ? s[tid - d] : 0;
        __syncthreads();
        s[tid] += v;
        __syncthreads();
    }
    int base = (tid == 0) ? 0 : s[tid - 1];
    for (int i = lo; i < hi; i++) {
        off[i] = base;
        base += cnt[i];
    }
}

// scatter: ATOMIC-FREE -- slot = off[dst] + rank.
__global__ __launch_bounds__(256) void scatter_kernel(
    const int* __restrict__ dst, const int* __restrict__ src,
    const int* __restrict__ off, const int* __restrict__ rank,
    int* __restrict__ eidx, int* __restrict__ srcs, int* __restrict__ dsts, int E)
{
    int i = blockIdx.x * 256 + threadIdx.x;
    if (i < E) {
        int p = off[dst[i]] + rank[i];
        eidx[p] = i;
        srcs[p] = src[i];
        dsts[p] = dst[i];
    }
}

// ---------------- edge tile kernel: 64 CSR slots per block ------------------
// exve16 (bf16) layout: [slot][64] = {ex[0..32), ve[32..64)}
__global__ __launch_bounds__(256, 4) void edge_tile_kernel(
    const float* __restrict__ edge, const unsigned short* __restrict__ qkv16,
    const int* __restrict__ eidx, const int* __restrict__ srcs,
    const int* __restrict__ dsts,
    const float* __restrict__ We, const float* __restrict__ be,
    const float* __restrict__ Wb, const float* __restrict__ bb,
    const float* __restrict__ Wf0, const float* __restrict__ bf0,
    const float* __restrict__ Wf1, const float* __restrict__ bf1,
    const float* __restrict__ ge0, const float* __restrict__ be0,
    const float* __restrict__ ge1, const float* __restrict__ be1,
    unsigned short* __restrict__ exve16, float* __restrict__ eout, int E)
{
    __shared__ float          sEV[64 * 36];   // ev -> er
    __shared__ unsigned short sQK[64 * 44];   // qk bf16 (pad 44)
    __shared__ unsigned short sA [64 * 40];   // ew/en bf16
    __shared__ unsigned short sB [64 * 40];   // Wb|We then Wf0
    __shared__ unsigned short sB2[32 * 72];   // Wf1^T
    __shared__ unsigned short sX [64 * 76];   // ex|ve then F (pad 76)
    // total 39,424 B -> 4 blocks/CU

    const int tid = threadIdx.x;
    const long long e0 = (long long)blockIdx.x * 64;
    const int w  = tid >> 6;
    const int l  = tid & 63;
    const int fr = l & 15;
    const int kg = l >> 4;

    // ---- S1a: fused score from bf16 qkv16 (q[dst] L1/L2-hot, CSR order) ----
    {
        const int row = tid >> 2;
        const int j   = tid & 3;
        long long s = e0 + row;
        float qv[24], kv[24];
        if (s < E) {
            int dn = dsts[s], sn = srcs[s];
            const unsigned short* qp = qkv16 + (size_t)dn * 288 + 24 * j;
            const unsigned short* kp = qkv16 + (size_t)sn * 288 + 96 + 24 * j;
            #pragma unroll
            for (int t = 0; t < 3; t++) {
                s16x8 qa = *(const s16x8*)(qp + 8 * t);
                s16x8 ka = *(const s16x8*)(kp + 8 * t);
                #pragma unroll
                for (int u = 0; u < 8; u++) {
                    qv[8 * t + u] = b2f((unsigned short)qa[u]);
                    kv[8 * t + u] = b2f((unsigned short)ka[u]);
                }
            }
        } else {
            #pragma unroll
            for (int t = 0; t < 24; t++) { qv[t] = 0.f; kv[t] = 0.f; }
        }
        s16x8 qkb;
        #pragma unroll
        for (int t = 0; t < 8; t++) {
            float d = kv[3*t]*qv[3*t] + kv[3*t+1]*qv[3*t+1] + kv[3*t+2]*qv[3*t+2];
            qkb[t] = (short)f2b(0.5f * d);
        }
        *(s16x8*)&sQK[row * 44 + 8 * j] = qkb;
    }

    // ---- S1b: stage ev (via eidx), Wb|We^T (bf16), Wf1^T (bf16) ----
    #pragma unroll
    for (int rr = 0; rr < 2; rr++) {
        int idx = tid + 256 * rr;
        int row = idx >> 3, c4 = (idx & 7) * 4;
        long long s = e0 + row;
        float4 v = make_float4(0.f, 0.f, 0.f, 0.f);
        if (s < E) {
            int ge = eidx[s];
            v = *(const float4*)(edge + (size_t)ge * 32 + c4);
        }
        *(float4*)&sEV[row * 36 + c4] = v;
    }
    {
        int k = tid >> 3, c4 = (tid & 7) * 4;
        float4 vb = *(const float4*)(Wb + k * 32 + c4);
        float4 ve = *(const float4*)(We + k * 32 + c4);
        sB[(c4 + 0) * 40 + k] = f2b(vb.x); sB[(c4 + 1) * 40 + k] = f2b(vb.y);
        sB[(c4 + 2) * 40 + k] = f2b(vb.z); sB[(c4 + 3) * 40 + k] = f2b(vb.w);
        sB[(32 + c4 + 0) * 40 + k] = f2b(ve.x); sB[(32 + c4 + 1) * 40 + k] = f2b(ve.y);
        sB[(32 + c4 + 2) * 40 + k] = f2b(ve.z); sB[(32 + c4 + 3) * 40 + k] = f2b(ve.w);
    }
    #pragma unroll
    for (int rr = 0; rr < 2; rr++) {
        int idx = tid + 256 * rr;
        int k = idx >> 3, c4 = (idx & 7) * 4;
        float4 v = *(const float4*)(Wf1 + k * 32 + c4);
        sB2[(c4 + 0) * 72 + k] = f2b(v.x); sB2[(c4 + 1) * 72 + k] = f2b(v.y);
        sB2[(c4 + 2) * 72 + k] = f2b(v.z); sB2[(c4 + 3) * 72 + k] = f2b(v.w);
    }
    __syncthreads();

    // ---- S2: LN1 -> ew rows (bf16) in sA ----
    {
        const int row = 16 * w + (tid & 15);
        const int q = (tid & 63) >> 4;
        float x[8];
        *(float4*)&x[0] = *(float4*)&sEV[row * 36 + 8 * q];
        *(float4*)&x[4] = *(float4*)&sEV[row * 36 + 8 * q + 4];
        float s = x[0] + x[1] + x[2] + x[3] + x[4] + x[5] + x[6] + x[7];
        s += __shfl_xor(s, 16, 64); s += __shfl_xor(s, 32, 64);
        float mu = s * (1.f / 32.f);
        float v2 = 0.f;
        #pragma unroll
        for (int i = 0; i < 8; i++) { float d = x[i] - mu; v2 += d * d; }
        v2 += __shfl_xor(v2, 16, 64); v2 += __shfl_xor(v2, 32, 64);
        float rs = rsqrtf(v2 * (1.f / 32.f) + 1e-5f);
        float4 g1 = *(const float4*)(ge0 + 8 * q), g2 = *(const float4*)(ge0 + 8 * q + 4);
        float4 b1 = *(const float4*)(be0 + 8 * q), b2 = *(const float4*)(be0 + 8 * q + 4);
        float gg[8] = {g1.x, g1.y, g1.z, g1.w, g2.x, g2.y, g2.z, g2.w};
        float bs[8] = {b1.x, b1.y, b1.z, b1.w, b2.x, b2.y, b2.z, b2.w};
        s16x8 y;
        #pragma unroll
        for (int i = 0; i < 8; i++)
            y[i] = (short)f2b((x[i] - mu) * rs * gg[i] + bs[i]);
        *(s16x8*)&sA[row * 40 + 8 * q] = y;
    }
    __syncthreads();

    // ---- S3: GEMM1 (MFMA)  [64][64 = sc|veh] = ew @ [Wb|We] ----
    f32x4 acc[4];
    {
        s16x8 a = *(s16x8*)&sA[(16 * w + fr) * 40 + kg * 8];
        #pragma unroll
        for (int nt = 0; nt < 4; nt++) {
            s16x8 b = *(s16x8*)&sB[(16 * nt + fr) * 40 + kg * 8];
            f32x4 z = {0.f, 0.f, 0.f, 0.f};
            acc[nt] = __builtin_amdgcn_mfma_f32_16x16x32_bf16(a, b, z, 0, 0, 0);
        }
    }
    __syncthreads();

    // ---- S4: epilogue1 (ex|ve -> sX; er -> sEV) + restage Wf0 -> sB ----
    #pragma unroll
    for (int nt = 0; nt < 2; nt++) {
        int col = nt * 16 + fr;
        float bbv = bb[col];
        #pragma unroll
        for (int r = 0; r < 4; r++) {
            int row = 16 * w + 4 * kg + r;
            float sc = acc[nt][r] + b2f(sQK[row * 44 + col]) + bbv;
            sX[row * 76 + col] = f2b(__expf(sc));
            float er = sc + sEV[row * 36 + col];
            sEV[row * 36 + col] = er;
        }
    }
    #pragma unroll
    for (int nt = 2; nt < 4; nt++) {
        int col = (nt - 2) * 16 + fr;
        float bev = be[col];
        #pragma unroll
        for (int r = 0; r < 4; r++) {
            int row = 16 * w + 4 * kg + r;
            sX[row * 76 + 32 + col] = f2b(acc[nt][r] + bev);
        }
    }
    #pragma unroll
    for (int rr = 0; rr < 2; rr++) {
        int idx = tid + 256 * rr;
        int k = idx >> 4, c4 = (idx & 15) * 4;
        float4 v = *(const float4*)(Wf0 + k * 64 + c4);
        sB[(c4 + 0) * 40 + k] = f2b(v.x); sB[(c4 + 1) * 40 + k] = f2b(v.y);
        sB[(c4 + 2) * 40 + k] = f2b(v.z); sB[(c4 + 3) * 40 + k] = f2b(v.w);
    }
    __syncthreads();

    // ---- S5: copy sX -> exve16 contiguously at slot ; LN2 -> sA ----
    #pragma unroll
    for (int rr = 0; rr < 2; rr++) {
        int idx = tid + 256 * rr;
        int row = idx >> 3, c8 = (idx & 7) * 8;
        long long s = e0 + row;
        if (s < E)
            *(s16x8*)(exve16 + (size_t)s * 64 + c8) = *(s16x8*)&sX[row * 76 + c8];
    }
    {
        const int row = 16 * w + (tid & 15);
        const int q = (tid & 63) >> 4;
        float x[8];
        *(float4*)&x[0] = *(float4*)&sEV[row * 36 + 8 * q];
        *(float4*)&x[4] = *(float4*)&sEV[row * 36 + 8 * q + 4];
        float s = x[0] + x[1] + x[2] + x[3] + x[4] + x[5] + x[6] + x[7];
        s += __shfl_xor(s, 16, 64); s += __shfl_xor(s, 32, 64);
        float mu = s * (1.f / 32.f);
        float v2 = 0.f;
        #pragma unroll
        for (int i = 0; i < 8; i++) { float d = x[i] - mu; v2 += d * d; }
        v2 += __shfl_xor(v2, 16, 64); v2 += __shfl_xor(v2, 32, 64);
        float rs = rsqrtf(v2 * (1.f / 32.f) + 1e-5f);
        float4 g1 = *(const float4*)(ge1 + 8 * q), g2 = *(const float4*)(ge1 + 8 * q + 4);
        float4 b1 = *(const float4*)(be1 + 8 * q), b2 = *(const float4*)(be1 + 8 * q + 4);
        float gg[8] = {g1.x, g1.y, g1.z, g1.w, g2.x, g2.y, g2.z, g2.w};
        float bs[8] = {b1.x, b1.y, b1.z, b1.w, b2.x, b2.y, b2.z, b2.w};
        s16x8 y;
        #pragma unroll
        for (int i = 0; i < 8; i++)
            y[i] = (short)f2b((x[i] - mu) * rs * gg[i] + bs[i]);
        *(s16x8*)&sA[row * 40 + 8 * q] = y;
    }
    __syncthreads();

    // ---- S6: GEMM2 (MFMA)  F[64][64] = relu(en @ Wf0 + bf0) -> sX ----
    {
        s16x8 a = *(s16x8*)&sA[(16 * w + fr) * 40 + kg * 8];
        #pragma unroll
        for (int nt = 0; nt < 4; nt++) {
            s16x8 b = *(s16x8*)&sB[(16 * nt + fr) * 40 + kg * 8];
            f32x4 z = {0.f, 0.f, 0.f, 0.f};
            f32x4 a2 = __builtin_amdgcn_mfma_f32_16x16x32_bf16(a, b, z, 0, 0, 0);
            int col = nt * 16 + fr;
            float b0v = bf0[col];
            #pragma unroll
            for (int r = 0; r < 4; r++) {
                int row = 16 * w + 4 * kg + r;
                sX[row * 76 + col] = f2b(fmaxf(a2[r] + b0v, 0.f));
            }
        }
    }
    __syncthreads();

    // ---- S7: GEMM3 (MFMA)  out[64][32] = F @ Wf1 + er + bf1 -> sEV ----
    {
        s16x8 a0 = *(s16x8*)&sX[(16 * w + fr) * 76 + kg * 8];
        s16x8 a1 = *(s16x8*)&sX[(16 * w + fr) * 76 + 32 + kg * 8];
        #pragma unroll
        for (int nt = 0; nt < 2; nt++) {
            s16x8 b0 = *(s16x8*)&sB2[(16 * nt + fr) * 72 + kg * 8];
            s16x8 b1 = *(s16x8*)&sB2[(16 * nt + fr) * 72 + 32 + kg * 8];
            f32x4 z = {0.f, 0.f, 0.f, 0.f};
            f32x4 t = __builtin_amdgcn_mfma_f32_16x16x32_bf16(a0, b0, z, 0, 0, 0);
            t = __builtin_amdgcn_mfma_f32_16x16x32_bf16(a1, b1, t, 0, 0, 0);
            int col = nt * 16 + fr;
            float bf1v = bf1[col];
            #pragma unroll
            for (int r = 0; r < 4; r++) {
                int row = 16 * w + 4 * kg + r;
                float out = t[r] + sEV[row * 36 + col] + bf1v;
                sEV[row * 36 + col] = out;
            }
        }
    }
    __syncthreads();

    // ---- S8: copy sEV[:, 0..32) -> eout[eidx[s]] ----
    #pragma unroll
    for (int rr = 0; rr < 2; rr++) {
        int idx = tid + 256 * rr;
        int row = idx >> 3, c4 = (idx & 7) * 4;
        long long s = e0 + row;
        if (s < E) {
            int ge = eidx[s];
            *(float4*)(eout + (size_t)ge * 32 + c4) = *(float4*)&sEV[row * 36 + c4];
        }
    }
}

// ---------------- gather: wave/node, 2 edges in flight per half ------------
__global__ __launch_bounds__(256) void gather_kernel(
    const unsigned short* __restrict__ exve16, const unsigned short* __restrict__ qkv16,
    const int* __restrict__ srcs, const int* __restrict__ off,
    const int* __restrict__ cnt, unsigned short* __restrict__ agg16, int N)
{
    __shared__ unsigned short sV16[4][2][2][96];
    __shared__ unsigned short sE16[4][2][2][64];
    const int wave = threadIdx.x >> 6;
    const int lane = threadIdx.x & 63;
    const int head = lane & 31;
    const int half = lane >> 5;
    int n = blockIdx.x * 4 + wave;
    if (n >= N) return;
    const int o = off[n], d = cnt[n];
    float a0 = 0.f, a1 = 0.f, a2 = 0.f, a3 = 0.f, den = 0.f;
    for (int i = half; i < d; i += 4) {
        const int i2 = i + 2;
        {
            int sn = srcs[o + i];
            const unsigned short* vr = qkv16 + (size_t)sn * 288 + 192;
            const unsigned short* er = exve16 + (size_t)(o + i) * 64;
            if (head < 12)
                *(s16x8*)&sV16[wave][half][0][head * 8] = *(const s16x8*)(vr + head * 8);
            else if (head >= 24)
                *(s16x8*)&sE16[wave][half][0][(head - 24) * 8] = *(const s16x8*)(er + (head - 24) * 8);
        }
        if (i2 < d) {
            int sn = srcs[o + i2];
            const unsigned short* vr = qkv16 + (size_t)sn * 288 + 192;
            const unsigned short* er = exve16 + (size_t)(o + i2) * 64;
            if (head < 12)
                *(s16x8*)&sV16[wave][half][1][head * 8] = *(const s16x8*)(vr + head * 8);
            else if (head >= 24)
                *(s16x8*)&sE16[wave][half][1][(head - 24) * 8] = *(const s16x8*)(er + (head - 24) * 8);
        }
        __builtin_amdgcn_wave_barrier();
        {
            float ex = b2f(sE16[wave][half][0][head]);
            float vv = b2f(sE16[wave][half][0][32 + head]);
            a0 += ex * b2f(sV16[wave][half][0][head * 3]);
            a1 += ex * b2f(sV16[wave][half][0][head * 3 + 1]);
            a2 += ex * b2f(sV16[wave][half][0][head * 3 + 2]);
            a3 += ex * vv;
            den += ex;
        }
        if (i2 < d) {
            float ex = b2f(sE16[wave][half][1][head]);
            float vv = b2f(sE16[wave][half][1][32 + head]);
            a0 += ex * b2f(sV16[wave][half][1][head * 3]);
            a1 += ex * b2f(sV16[wave][half][1][head * 3 + 1]);
            a2 += ex * b2f(sV16[wave][half][1][head * 3 + 2]);
            a3 += ex * vv;
            den += ex;
        }
        __builtin_amdgcn_wave_barrier();
    }
    a0 += __shfl_xor(a0, 32, 64);
    a1 += __shfl_xor(a1, 32, 64);
    a2 += __shfl_xor(a2, 32, 64);
    a3 += __shfl_xor(a3, 32, 64);
    den += __shfl_xor(den, 32, 64);
    if (half == 0) {
        float sc = (d > 0) ? 1.f / den : 0.f;
        s16x4 ov;
        ov[0] = (short)f2b(a0 * sc);
        ov[1] = (short)f2b(a1 * sc);
        ov[2] = (short)f2b(a2 * sc);
        ov[3] = (short)f2b(a3 * sc);
        *(s16x4*)(agg16 + (size_t)n * 128 + head * 4) = ov;
    }
}

// ---------------------------------------------------------------------------
extern "C" void kernel_launch(void* const* d_in, const int* in_sizes, int n_in,
                              void* d_out, int out_size, void* d_ws, size_t ws_size,
                              hipStream_t stream)
{
    (void)n_in; (void)out_size; (void)ws_size;
    const float* feat = (const float*)d_in[0];
    const float* edge = (const float*)d_in[1];
    const float* Wq   = (const float*)d_in[2];
    const float* bq   = (const float*)d_in[3];
    const float* Wk   = (const float*)d_in[4];
    const float* bk   = (const float*)d_in[5];
    const float* Wv   = (const float*)d_in[6];
    const float* bv   = (const float*)d_in[7];
    const float* We   = (const float*)d_in[8];
    const float* be   = (const float*)d_in[9];
    const float* Wb   = (const float*)d_in[10];
    const float* bb   = (const float*)d_in[11];
    const float* Wvv  = (const float*)d_in[12];
    const float* bvv  = (const float*)d_in[13];
    const float* Wf0  = (const float*)d_in[14];
    const float* bf0  = (const float*)d_in[15];
    const float* Wf1  = (const float*)d_in[16];
    const float* bf1  = (const float*)d_in[17];
    const float* Wm0  = (const float*)d_in[18];
    const float* bm0  = (const float*)d_in[19];
    const float* Wm1  = (const float*)d_in[20];
    const float* bm1  = (const float*)d_in[21];
    const float* g_n0 = (const float*)d_in[22];
    const float* b_n0 = (const float*)d_in[23];
    const float* g_e0 = (const float*)d_in[24];
    const float* b_e0 = (const float*)d_in[25];
    const float* g_e1 = (const float*)d_in[26];
    const float* b_e1 = (const float*)d_in[27];
    const float* g_m  = (const float*)d_in[28];
    const float* b_m  = (const float*)d_in[29];
    const float* wsc  = (const float*)d_in[30];
    const int*   src  = (const int*)d_in[31];
    const int*   dst  = (const int*)d_in[32];

    const int N = in_sizes[0] / 96;
    const int E = in_sizes[1] / 32;

    float* ws    = (float*)d_ws;
    float* hp    = ws;                                      // N*96 f32
    float* tbuf  = hp + (size_t)N * 96;                     // N*192 f32
    unsigned short* agg16 = (unsigned short*)(tbuf + (size_t)N * 192); // N*128 bf16
    unsigned short* qkv16 = agg16 + (size_t)N * 128;        // N*288 bf16
    unsigned short* exve16 = qkv16 + (size_t)N * 288;       // E*64 bf16
    int*   eidx  = (int*)(exve16 + (size_t)E * 64);         // E
    int*   rank  = eidx + E;                                // E
    int*   srcs  = rank + E;                                // E
    int*   dsts  = srcs + E;                                // E
    int*   cnt   = dsts + E;                                // N
    int*   offv  = cnt + N;                                 // N
    float* hout  = (float*)d_out;
    float* eoutp = (float*)d_out + (size_t)N * 96;

    hipMemsetAsync(cnt, 0, (size_t)N * sizeof(int), stream);

    const int mt = (N + 63) / 64;
    const int et = (E + 255) / 256;

    // CSR bucketing: one atomic pass + scan + atomic-free scatter
    count_kernel<<<et, 256, 0, stream>>>(dst, cnt, rank, E);
    scan_kernel<<<1, 1024, 0, stream>>>(cnt, offv, N);
    scatter_kernel<<<et, 256, 0, stream>>>(dst, src, offv, rank, eidx, srcs, dsts, E);

    // qkv16 = bf16( LN(feat) @ [Wq|Wk|Wv] )  (LN fused; bf16-only output)
    mgemm_kernel<1,1,0,0,0><<<dim3(mt, 3), 256, 0, stream>>>(
        feat, 96, Wq, Wk, Wv, 96, bq, bk, bv, g_n0, b_n0,
        nullptr, nullptr, nullptr, 0, qkv16, N, 96);

    // fused edge tile pass (CSR slot order, bf16 q/k)
    edge_tile_kernel<<<(E + 63) / 64, 256, 0, stream>>>(edge, qkv16, eidx, srcs, dsts,
                                             We, be, Wb, bb, Wf0, bf0, Wf1, bf1,
                                             g_e0, b_e0, g_e1, b_e1,
                                             exve16, eoutp, E);

    // gather per node -> normalized agg16[N,128] (bf16)
    gather_kernel<<<(N + 3) / 4, 256, 0, stream>>>(exve16, qkv16, srcs, offv, cnt, agg16, N);

    // h_pre = feat*(1+w) + agg @ Wvv + bvv   (bf16 A)
    mgemm_kernel<0,0,1,0,1><<<dim3(mt, 1), 256, 0, stream>>>(
        agg16, 128, Wvv, Wvv, Wvv, 96, bvv, bvv, bvv, nullptr, nullptr,
        feat, wsc, hp, 96, nullptr, N, 128);
    // t = relu(LN(hp) @ Wm0 + bm0)   (LN fused)
    mgemm_kernel<0,1,0,1,0><<<dim3(mt, 2), 256, 0, stream>>>(
        hp, 96, Wm0, Wm0, Wm0, 192, bm0, bm0, bm0, g_m, b_m,
        nullptr, nullptr, tbuf, 192, nullptr, N, 96);
    // h_out = hp + t @ Wm1 + bm1
    mgemm_kernel<0,0,0,0,1><<<dim3(mt, 1), 256, 0, stream>>>(
        tbuf, 192, Wm1, Wm1, Wm1, 96, bm1, bm1, bm1, nullptr, nullptr,
        hp, nullptr, hout, 96, nullptr, N, 192);
}

// Round 17
// 818.832 us; speedup vs baseline: 1.3600x; 1.0097x over previous
//
#include <hip/hip_runtime.h>
#include <cstdint>
#include <cstddef>

// ---------------------------------------------------------------------------
// EGT layer.  N nodes (DIM=96, H=32, HD=3), E edges.
// prep_kernel: converts edge weights ONCE to MFMA-ready bf16 [N][K] layouts.
// edge_tile_kernel: 64 CSR slots per block; B-fragments read directly from
// global (L1-resident weights), 4 syncthreads, 29.7 KB LDS -> 5 blocks/CU.
// Bucketing: count emits rank; scatter atomic-free.  qkv bf16-only.
// ---------------------------------------------------------------------------

typedef short  s16x8 __attribute__((ext_vector_type(8)));
typedef short  s16x4 __attribute__((ext_vector_type(4)));
typedef float  f32x4 __attribute__((ext_vector_type(4)));

__device__ __forceinline__ unsigned short f2b(float x) {
    union { float f; unsigned u; } v; v.f = x;
    unsigned r = v.u + 0x7FFF + ((v.u >> 16) & 1);   // RNE
    return (unsigned short)(r >> 16);
}
__device__ __forceinline__ float b2f(unsigned short u) {
    union { unsigned u; float f; } v; v.u = ((unsigned)u) << 16; return v.f;
}

// ---------------- MFMA node GEMM ----------------
template<int MULTI, int LNA, int A16, int RELU, int RES>
__global__ __launch_bounds__(256) void mgemm_kernel(
    const void* __restrict__ Av, int lda,
    const float* __restrict__ B0, const float* __restrict__ B1,
    const float* __restrict__ B2, int ldb,
    const float* __restrict__ bias0, const float* __restrict__ bias1,
    const float* __restrict__ bias2,
    const float* __restrict__ lng, const float* __restrict__ lnbv,
    const float* __restrict__ resid, const float* __restrict__ wptr,
    float* __restrict__ C, int ldc, unsigned short* __restrict__ C16,
    int M, int K)
{
    __shared__ unsigned short sAL[64 * 200];
    __shared__ unsigned short sB[96 * 40];

    const int tid = threadIdx.x;
    const int m0 = blockIdx.x * 64;
    const int y  = blockIdx.y;
    const float* B = MULTI ? (y == 0 ? B0 : (y == 1 ? B1 : B2)) : B0;
    const int nbB = MULTI ? 0 : y * 96;
    const int nbC = y * 96;
    const int w = tid >> 6, l = tid & 63, fr = l & 15, kg = l >> 4;
    const int KP = K + 8;

    if (LNA) {
        const float* Af = (const float*)Av;
        const int row = 16 * w + fr;
        const int grow = m0 + row;
        float x[24];
        if (grow < M) {
            #pragma unroll
            for (int t = 0; t < 6; t++)
                *(float4*)&x[t * 4] = *(const float4*)(Af + (size_t)grow * lda + 24 * kg + t * 4);
        } else {
            #pragma unroll
            for (int t = 0; t < 24; t++) x[t] = 0.f;
        }
        float s = 0.f;
        #pragma unroll
        for (int t = 0; t < 24; t++) s += x[t];
        s += __shfl_xor(s, 16, 64); s += __shfl_xor(s, 32, 64);
        float mu = s * (1.f / 96.f);
        float v2 = 0.f;
        #pragma unroll
        for (int t = 0; t < 24; t++) { float d = x[t] - mu; v2 += d * d; }
        v2 += __shfl_xor(v2, 16, 64); v2 += __shfl_xor(v2, 32, 64);
        float rs = rsqrtf(v2 * (1.f / 96.f) + 1e-5f);
        #pragma unroll
        for (int t3 = 0; t3 < 3; t3++) {
            s16x8 yv;
            #pragma unroll
            for (int u = 0; u < 8; u++) {
                int cidx = 24 * kg + t3 * 8 + u;
                yv[u] = (short)f2b((x[t3 * 8 + u] - mu) * rs * lng[cidx] + lnbv[cidx]);
            }
            *(s16x8*)&sAL[row * KP + 24 * kg + t3 * 8] = yv;
        }
    } else {
        const int nseg = K >> 3;
        for (int idx = tid; idx < 64 * nseg; idx += 256) {
            int row = idx / nseg, k8 = (idx - row * nseg) * 8;
            int grow = m0 + row;
            s16x8 a8 = (s16x8){0, 0, 0, 0, 0, 0, 0, 0};
            if (grow < M) {
                if (A16) {
                    a8 = *(const s16x8*)((const unsigned short*)Av + (size_t)grow * lda + k8);
                } else {
                    const float* Af = (const float*)Av;
                    float4 v0 = *(const float4*)(Af + (size_t)grow * lda + k8);
                    float4 v1 = *(const float4*)(Af + (size_t)grow * lda + k8 + 4);
                    a8[0] = (short)f2b(v0.x); a8[1] = (short)f2b(v0.y);
                    a8[2] = (short)f2b(v0.z); a8[3] = (short)f2b(v0.w);
                    a8[4] = (short)f2b(v1.x); a8[5] = (short)f2b(v1.y);
                    a8[6] = (short)f2b(v1.z); a8[7] = (short)f2b(v1.w);
                }
            }
            *(s16x8*)&sAL[row * KP + k8] = a8;
        }
    }

    f32x4 acc[6];
    #pragma unroll
    for (int i = 0; i < 6; i++) acc[i] = (f32x4){0.f, 0.f, 0.f, 0.f};

    for (int kc = 0; kc < K; kc += 32) {
        #pragma unroll
        for (int r = 0; r < 3; r++) {
            int idx = tid + 256 * r;
            int k = idx / 24, n4 = (idx - k * 24) * 4;
            float4 v = *(const float4*)(B + (size_t)(kc + k) * ldb + nbB + n4);
            sB[(n4 + 0) * 40 + k] = f2b(v.x);
            sB[(n4 + 1) * 40 + k] = f2b(v.y);
            sB[(n4 + 2) * 40 + k] = f2b(v.z);
            sB[(n4 + 3) * 40 + k] = f2b(v.w);
        }
        __syncthreads();
        {
            s16x8 a = *(s16x8*)&sAL[(16 * w + fr) * KP + kc + kg * 8];
            #pragma unroll
            for (int nt = 0; nt < 6; nt++) {
                s16x8 b = *(s16x8*)&sB[(16 * nt + fr) * 40 + kg * 8];
                acc[nt] = __builtin_amdgcn_mfma_f32_16x16x32_bf16(a, b, acc[nt], 0, 0, 0);
            }
        }
        __syncthreads();
    }

    float scale = 1.f;
    if (RES) scale = wptr ? (1.f + wptr[0]) : 1.f;
    const float* biasp = MULTI ? (y == 0 ? bias0 : (y == 1 ? bias1 : bias2)) : bias0;
    const int bbase = MULTI ? 0 : nbB;

    #pragma unroll
    for (int nt = 0; nt < 6; nt++) {
        int cl = nt * 16 + fr;
        float bv = biasp[bbase + cl];
        int gcol = nbC + cl;
        #pragma unroll
        for (int r = 0; r < 4; r++) {
            int row = m0 + 16 * w + 4 * kg + r;
            if (row >= M) continue;
            float v = acc[nt][r] + bv;
            if (RELU) v = fmaxf(v, 0.f);
            if (MULTI) {
                C16[(size_t)row * 288 + gcol] = f2b(v);
            } else {
                if (RES) v += scale * resid[(size_t)row * ldc + gcol];
                C[(size_t)row * ldc + gcol] = v;
            }
        }
    }
}

// ---------------- prep: edge weights -> bf16 [N][K] layouts (once) ---------
__global__ __launch_bounds__(256) void prep_kernel(
    const float* __restrict__ Wb, const float* __restrict__ We,
    const float* __restrict__ Wf0, const float* __restrict__ Wf1,
    unsigned short* __restrict__ WbWe16, unsigned short* __restrict__ Wf0T16,
    unsigned short* __restrict__ Wf1T16)
{
    const int t = threadIdx.x;
    for (int i = t; i < 2048; i += 256) {
        int n = i >> 5, k = i & 31;
        float v = (n < 32) ? Wb[k * 32 + n] : We[k * 32 + (n - 32)];
        WbWe16[i] = f2b(v);
    }
    for (int i = t; i < 2048; i += 256) {
        int n = i >> 5, k = i & 31;
        Wf0T16[i] = f2b(Wf0[k * 64 + n]);
    }
    for (int i = t; i < 2048; i += 256) {
        int n = i >> 6, k = i & 63;
        Wf1T16[i] = f2b(Wf1[k * 32 + n]);
    }
}

// ---------------- CSR bucketing ----------------
__global__ __launch_bounds__(256) void count_kernel(
    const int* __restrict__ dst, int* __restrict__ cnt,
    int* __restrict__ rank, int E)
{
    int i = blockIdx.x * 256 + threadIdx.x;
    if (i < E) rank[i] = atomicAdd(&cnt[dst[i]], 1);
}

__global__ __launch_bounds__(1024) void scan_kernel(
    const int* __restrict__ cnt, int* __restrict__ off, int N)
{
    __shared__ int s[1024];
    const int tid = threadIdx.x;
    const int chunk = (N + 1023) >> 10;
    const int lo = tid * chunk;
    const int hi = min(lo + chunk, N);
    int sum = 0;
    for (int i = lo; i < hi; i++) sum += cnt[i];
    s[tid] = sum;
    __syncthreads();
    for (int d = 1; d < 1024; d <<= 1) {
        int v = (tid >= d) ? s[tid - d] : 0;
        __syncthreads();
        s[tid] += v;
        __syncthreads();
    }
    int base = (tid == 0) ? 0 : s[tid - 1];
    for (int i = lo; i < hi; i++) {
        off[i] = base;
        base += cnt[i];
    }
}

__global__ __launch_bounds__(256) void scatter_kernel(
    const int* __restrict__ dst, const int* __restrict__ src,
    const int* __restrict__ off, const int* __restrict__ rank,
    int* __restrict__ eidx, int* __restrict__ srcs, int* __restrict__ dsts, int E)
{
    int i = blockIdx.x * 256 + threadIdx.x;
    if (i < E) {
        int p = off[dst[i]] + rank[i];
        eidx[p] = i;
        srcs[p] = src[i];
        dsts[p] = dst[i];
    }
}

// ---------------- edge tile kernel: 64 CSR slots per block ------------------
// exve16 (bf16) layout: [slot][64] = {ex[0..32), ve[32..64)}
__global__ __launch_bounds__(256, 5) void edge_tile_kernel(
    const float* __restrict__ edge, const unsigned short* __restrict__ qkv16,
    const int* __restrict__ eidx, const int* __restrict__ srcs,
    const int* __restrict__ dsts,
    const unsigned short* __restrict__ WbWe16,
    const unsigned short* __restrict__ Wf0T16,
    const unsigned short* __restrict__ Wf1T16,
    const float* __restrict__ be, const float* __restrict__ bb,
    const float* __restrict__ bf0, const float* __restrict__ bf1,
    const float* __restrict__ ge0, const float* __restrict__ be0,
    const float* __restrict__ ge1, const float* __restrict__ be1,
    unsigned short* __restrict__ exve16, float* __restrict__ eout, int E)
{
    __shared__ float          sEV[64 * 36];   // ev -> er
    __shared__ unsigned short sQK[64 * 44];   // qk bf16 (pad 44)
    __shared__ unsigned short sA [64 * 40];   // ew/en bf16
    __shared__ unsigned short sX [64 * 76];   // ex|ve then F (pad 76)
    // total 29,696 B -> 5 blocks/CU

    const int tid = threadIdx.x;
    const long long e0 = (long long)blockIdx.x * 64;
    const int w  = tid >> 6;
    const int l  = tid & 63;
    const int fr = l & 15;
    const int kg = l >> 4;

    // ---- S1a: fused score from bf16 qkv16 (CSR order, q[dst] hot) ----
    {
        const int row = tid >> 2;
        const int j   = tid & 3;
        long long s = e0 + row;
        float qv[24], kv[24];
        if (s < E) {
            int dn = dsts[s], sn = srcs[s];
            const unsigned short* qp = qkv16 + (size_t)dn * 288 + 24 * j;
            const unsigned short* kp = qkv16 + (size_t)sn * 288 + 96 + 24 * j;
            #pragma unroll
            for (int t = 0; t < 3; t++) {
                s16x8 qa = *(const s16x8*)(qp + 8 * t);
                s16x8 ka = *(const s16x8*)(kp + 8 * t);
                #pragma unroll
                for (int u = 0; u < 8; u++) {
                    qv[8 * t + u] = b2f((unsigned short)qa[u]);
                    kv[8 * t + u] = b2f((unsigned short)ka[u]);
                }
            }
        } else {
            #pragma unroll
            for (int t = 0; t < 24; t++) { qv[t] = 0.f; kv[t] = 0.f; }
        }
        s16x8 qkb;
        #pragma unroll
        for (int t = 0; t < 8; t++) {
            float d = kv[3*t]*qv[3*t] + kv[3*t+1]*qv[3*t+1] + kv[3*t+2]*qv[3*t+2];
            qkb[t] = (short)f2b(0.5f * d);
        }
        *(s16x8*)&sQK[row * 44 + 8 * j] = qkb;
    }
    // ---- S1b: stage ev rows (via eidx) ----
    #pragma unroll
    for (int rr = 0; rr < 2; rr++) {
        int idx = tid + 256 * rr;
        int row = idx >> 3, c4 = (idx & 7) * 4;
        long long s = e0 + row;
        float4 v = make_float4(0.f, 0.f, 0.f, 0.f);
        if (s < E) {
            int ge = eidx[s];
            v = *(const float4*)(edge + (size_t)ge * 32 + c4);
        }
        *(float4*)&sEV[row * 36 + c4] = v;
    }
    __syncthreads();

    // ---- S2: LN1 -> ew rows (bf16) in sA (wave-local rows) ----
    {
        const int row = 16 * w + (tid & 15);
        const int q = (tid & 63) >> 4;
        float x[8];
        *(float4*)&x[0] = *(float4*)&sEV[row * 36 + 8 * q];
        *(float4*)&x[4] = *(float4*)&sEV[row * 36 + 8 * q + 4];
        float s = x[0] + x[1] + x[2] + x[3] + x[4] + x[5] + x[6] + x[7];
        s += __shfl_xor(s, 16, 64); s += __shfl_xor(s, 32, 64);
        float mu = s * (1.f / 32.f);
        float v2 = 0.f;
        #pragma unroll
        for (int i = 0; i < 8; i++) { float d = x[i] - mu; v2 += d * d; }
        v2 += __shfl_xor(v2, 16, 64); v2 += __shfl_xor(v2, 32, 64);
        float rs = rsqrtf(v2 * (1.f / 32.f) + 1e-5f);
        float4 g1 = *(const float4*)(ge0 + 8 * q), g2 = *(const float4*)(ge0 + 8 * q + 4);
        float4 b1 = *(const float4*)(be0 + 8 * q), b2 = *(const float4*)(be0 + 8 * q + 4);
        float gg[8] = {g1.x, g1.y, g1.z, g1.w, g2.x, g2.y, g2.z, g2.w};
        float bs[8] = {b1.x, b1.y, b1.z, b1.w, b2.x, b2.y, b2.z, b2.w};
        s16x8 y;
        #pragma unroll
        for (int i = 0; i < 8; i++)
            y[i] = (short)f2b((x[i] - mu) * rs * gg[i] + bs[i]);
        *(s16x8*)&sA[row * 40 + 8 * q] = y;
    }
    __builtin_amdgcn_wave_barrier();

    // ---- S3: GEMM1 (MFMA)  [64][64 = sc|veh] = ew @ [Wb|We] (B from L1) ----
    f32x4 acc[4];
    {
        s16x8 a = *(s16x8*)&sA[(16 * w + fr) * 40 + kg * 8];
        #pragma unroll
        for (int nt = 0; nt < 4; nt++) {
            s16x8 b = *(const s16x8*)(WbWe16 + (16 * nt + fr) * 32 + kg * 8);
            f32x4 z = {0.f, 0.f, 0.f, 0.f};
            acc[nt] = __builtin_amdgcn_mfma_f32_16x16x32_bf16(a, b, z, 0, 0, 0);
        }
    }

    // ---- S4: epilogue1 (ex|ve -> sX; er -> sEV), all wave-local rows ----
    #pragma unroll
    for (int nt = 0; nt < 2; nt++) {
        int col = nt * 16 + fr;
        float bbv = bb[col];
        #pragma unroll
        for (int r = 0; r < 4; r++) {
            int row = 16 * w + 4 * kg + r;
            float sc = acc[nt][r] + b2f(sQK[row * 44 + col]) + bbv;
            sX[row * 76 + col] = f2b(__expf(sc));
            float er = sc + sEV[row * 36 + col];
            sEV[row * 36 + col] = er;
        }
    }
    #pragma unroll
    for (int nt = 2; nt < 4; nt++) {
        int col = (nt - 2) * 16 + fr;
        float bev = be[col];
        #pragma unroll
        for (int r = 0; r < 4; r++) {
            int row = 16 * w + 4 * kg + r;
            sX[row * 76 + 32 + col] = f2b(acc[nt][r] + bev);
        }
    }
    __syncthreads();

    // ---- S5a: copy sX -> exve16 (contiguous at slot); S5b: LN2 -> sA ----
    #pragma unroll
    for (int rr = 0; rr < 2; rr++) {
        int idx = tid + 256 * rr;
        int row = idx >> 3, c8 = (idx & 7) * 8;
        long long s = e0 + row;
        if (s < E)
            *(s16x8*)(exve16 + (size_t)s * 64 + c8) = *(s16x8*)&sX[row * 76 + c8];
    }
    {
        const int row = 16 * w + (tid & 15);
        const int q = (tid & 63) >> 4;
        float x[8];
        *(float4*)&x[0] = *(float4*)&sEV[row * 36 + 8 * q];
        *(float4*)&x[4] = *(float4*)&sEV[row * 36 + 8 * q + 4];
        float s = x[0] + x[1] + x[2] + x[3] + x[4] + x[5] + x[6] + x[7];
        s += __shfl_xor(s, 16, 64); s += __shfl_xor(s, 32, 64);
        float mu = s * (1.f / 32.f);
        float v2 = 0.f;
        #pragma unroll
        for (int i = 0; i < 8; i++) { float d = x[i] - mu; v2 += d * d; }
        v2 += __shfl_xor(v2, 16, 64); v2 += __shfl_xor(v2, 32, 64);
        float rs = rsqrtf(v2 * (1.f / 32.f) + 1e-5f);
        float4 g1 = *(const float4*)(ge1 + 8 * q), g2 = *(const float4*)(ge1 + 8 * q + 4);
        float4 b1 = *(const float4*)(be1 + 8 * q), b2 = *(const float4*)(be1 + 8 * q + 4);
        float gg[8] = {g1.x, g1.y, g1.z, g1.w, g2.x, g2.y, g2.z, g2.w};
        float bs[8] = {b1.x, b1.y, b1.z, b1.w, b2.x, b2.y, b2.z, b2.w};
        s16x8 y;
        #pragma unroll
        for (int i = 0; i < 8; i++)
            y[i] = (short)f2b((x[i] - mu) * rs * gg[i] + bs[i]);
        *(s16x8*)&sA[row * 40 + 8 * q] = y;
    }
    __syncthreads();   // sX must be fully copied out before S6 overwrites it

    // ---- S6: GEMM2 (MFMA)  F[64][64] = relu(en @ Wf0 + bf0) -> sX ----
    {
        s16x8 a = *(s16x8*)&sA[(16 * w + fr) * 40 + kg * 8];
        #pragma unroll
        for (int nt = 0; nt < 4; nt++) {
            s16x8 b = *(const s16x8*)(Wf0T16 + (16 * nt + fr) * 32 + kg * 8);
            f32x4 z = {0.f, 0.f, 0.f, 0.f};
            f32x4 a2 = __builtin_amdgcn_mfma_f32_16x16x32_bf16(a, b, z, 0, 0, 0);
            int col = nt * 16 + fr;
            float b0v = bf0[col];
            #pragma unroll
            for (int r = 0; r < 4; r++) {
                int row = 16 * w + 4 * kg + r;
                sX[row * 76 + col] = f2b(fmaxf(a2[r] + b0v, 0.f));
            }
        }
    }
    __builtin_amdgcn_wave_barrier();

    // ---- S7: GEMM3 (MFMA)  out[64][32] = F @ Wf1 + er + bf1 -> sEV ----
    {
        s16x8 a0 = *(s16x8*)&sX[(16 * w + fr) * 76 + kg * 8];
        s16x8 a1 = *(s16x8*)&sX[(16 * w + fr) * 76 + 32 + kg * 8];
        #pragma unroll
        for (int nt = 0; nt < 2; nt++) {
            s16x8 b0 = *(const s16x8*)(Wf1T16 + (16 * nt + fr) * 64 + kg * 8);
            s16x8 b1 = *(const s16x8*)(Wf1T16 + (16 * nt + fr) * 64 + 32 + kg * 8);
            f32x4 z = {0.f, 0.f, 0.f, 0.f};
            f32x4 t = __builtin_amdgcn_mfma_f32_16x16x32_bf16(a0, b0, z, 0, 0, 0);
            t = __builtin_amdgcn_mfma_f32_16x16x32_bf16(a1, b1, t, 0, 0, 0);
            int col = nt * 16 + fr;
            float bf1v = bf1[col];
            #pragma unroll
            for (int r = 0; r < 4; r++) {
                int row = 16 * w + 4 * kg + r;
                float out = t[r] + sEV[row * 36 + col] + bf1v;
                sEV[row * 36 + col] = out;
            }
        }
    }
    __syncthreads();

    // ---- S8: copy sEV[:, 0..32) -> eout[eidx[s]] ----
    #pragma unroll
    for (int rr = 0; rr < 2; rr++) {
        int idx = tid + 256 * rr;
        int row = idx >> 3, c4 = (idx & 7) * 4;
        long long s = e0 + row;
        if (s < E) {
            int ge = eidx[s];
            *(float4*)(eout + (size_t)ge * 32 + c4) = *(float4*)&sEV[row * 36 + c4];
        }
    }
}

// ---------------- gather: wave/node, 2 edges in flight per half ------------
__global__ __launch_bounds__(256) void gather_kernel(
    const unsigned short* __restrict__ exve16, const unsigned short* __restrict__ qkv16,
    const int* __restrict__ srcs, const int* __restrict__ off,
    const int* __restrict__ cnt, unsigned short* __restrict__ agg16, int N)
{
    __shared__ unsigned short sV16[4][2][2][96];
    __shared__ unsigned short sE16[4][2][2][64];
    const int wave = threadIdx.x >> 6;
    const int lane = threadIdx.x & 63;
    const int head = lane & 31;
    const int half = lane >> 5;
    int n = blockIdx.x * 4 + wave;
    if (n >= N) return;
    const int o = off[n], d = cnt[n];
    float a0 = 0.f, a1 = 0.f, a2 = 0.f, a3 = 0.f, den = 0.f;
    for (int i = half; i < d; i += 4) {
        const int i2 = i + 2;
        {
            int sn = srcs[o + i];
            const unsigned short* vr = qkv16 + (size_t)sn * 288 + 192;
            const unsigned short* er = exve16 + (size_t)(o + i) * 64;
            if (head < 12)
                *(s16x8*)&sV16[wave][half][0][head * 8] = *(const s16x8*)(vr + head * 8);
            else if (head >= 24)
                *(s16x8*)&sE16[wave][half][0][(head - 24) * 8] = *(const s16x8*)(er + (head - 24) * 8);
        }
        if (i2 < d) {
            int sn = srcs[o + i2];
            const unsigned short* vr = qkv16 + (size_t)sn * 288 + 192;
            const unsigned short* er = exve16 + (size_t)(o + i2) * 64;
            if (head < 12)
                *(s16x8*)&sV16[wave][half][1][head * 8] = *(const s16x8*)(vr + head * 8);
            else if (head >= 24)
                *(s16x8*)&sE16[wave][half][1][(head - 24) * 8] = *(const s16x8*)(er + (head - 24) * 8);
        }
        __builtin_amdgcn_wave_barrier();
        {
            float ex = b2f(sE16[wave][half][0][head]);
            float vv = b2f(sE16[wave][half][0][32 + head]);
            a0 += ex * b2f(sV16[wave][half][0][head * 3]);
            a1 += ex * b2f(sV16[wave][half][0][head * 3 + 1]);
            a2 += ex * b2f(sV16[wave][half][0][head * 3 + 2]);
            a3 += ex * vv;
            den += ex;
        }
        if (i2 < d) {
            float ex = b2f(sE16[wave][half][1][head]);
            float vv = b2f(sE16[wave][half][1][32 + head]);
            a0 += ex * b2f(sV16[wave][half][1][head * 3]);
            a1 += ex * b2f(sV16[wave][half][1][head * 3 + 1]);
            a2 += ex * b2f(sV16[wave][half][1][head * 3 + 2]);
            a3 += ex * vv;
            den += ex;
        }
        __builtin_amdgcn_wave_barrier();
    }
    a0 += __shfl_xor(a0, 32, 64);
    a1 += __shfl_xor(a1, 32, 64);
    a2 += __shfl_xor(a2, 32, 64);
    a3 += __shfl_xor(a3, 32, 64);
    den += __shfl_xor(den, 32, 64);
    if (half == 0) {
        float sc = (d > 0) ? 1.f / den : 0.f;
        s16x4 ov;
        ov[0] = (short)f2b(a0 * sc);
        ov[1] = (short)f2b(a1 * sc);
        ov[2] = (short)f2b(a2 * sc);
        ov[3] = (short)f2b(a3 * sc);
        *(s16x4*)(agg16 + (size_t)n * 128 + head * 4) = ov;
    }
}

// ---------------------------------------------------------------------------
extern "C" void kernel_launch(void* const* d_in, const int* in_sizes, int n_in,
                              void* d_out, int out_size, void* d_ws, size_t ws_size,
                              hipStream_t stream)
{
    (void)n_in; (void)out_size; (void)ws_size;
    const float* feat = (const float*)d_in[0];
    const float* edge = (const float*)d_in[1];
    const float* Wq   = (const float*)d_in[2];
    const float* bq   = (const float*)d_in[3];
    const float* Wk   = (const float*)d_in[4];
    const float* bk   = (const float*)d_in[5];
    const float* Wv   = (const float*)d_in[6];
    const float* bv   = (const float*)d_in[7];
    const float* We   = (const float*)d_in[8];
    const float* be   = (const float*)d_in[9];
    const float* Wb   = (const float*)d_in[10];
    const float* bb   = (const float*)d_in[11];
    const float* Wvv  = (const float*)d_in[12];
    const float* bvv  = (const float*)d_in[13];
    const float* Wf0  = (const float*)d_in[14];
    const float* bf0  = (const float*)d_in[15];
    const float* Wf1  = (const float*)d_in[16];
    const float* bf1  = (const float*)d_in[17];
    const float* Wm0  = (const float*)d_in[18];
    const float* bm0  = (const float*)d_in[19];
    const float* Wm1  = (const float*)d_in[20];
    const float* bm1  = (const float*)d_in[21];
    const float* g_n0 = (const float*)d_in[22];
    const float* b_n0 = (const float*)d_in[23];
    const float* g_e0 = (const float*)d_in[24];
    const float* b_e0 = (const float*)d_in[25];
    const float* g_e1 = (const float*)d_in[26];
    const float* b_e1 = (const float*)d_in[27];
    const float* g_m  = (const float*)d_in[28];
    const float* b_m  = (const float*)d_in[29];
    const float* wsc  = (const float*)d_in[30];
    const int*   src  = (const int*)d_in[31];
    const int*   dst  = (const int*)d_in[32];

    const int N = in_sizes[0] / 96;
    const int E = in_sizes[1] / 32;

    float* ws    = (float*)d_ws;
    float* hp    = ws;                                      // N*96 f32
    float* tbuf  = hp + (size_t)N * 96;                     // N*192 f32
    unsigned short* agg16 = (unsigned short*)(tbuf + (size_t)N * 192); // N*128 bf16
    unsigned short* qkv16 = agg16 + (size_t)N * 128;        // N*288 bf16
    unsigned short* exve16 = qkv16 + (size_t)N * 288;       // E*64 bf16
    unsigned short* wbwe16 = exve16 + (size_t)E * 64;       // 2048
    unsigned short* wf0t16 = wbwe16 + 2048;                 // 2048
    unsigned short* wf1t16 = wf0t16 + 2048;                 // 2048
    int*   eidx  = (int*)(wf1t16 + 2048);                   // E
    int*   rank  = eidx + E;                                // E
    int*   srcs  = rank + E;                                // E
    int*   dsts  = srcs + E;                                // E
    int*   cnt   = dsts + E;                                // N
    int*   offv  = cnt + N;                                 // N
    float* hout  = (float*)d_out;
    float* eoutp = (float*)d_out + (size_t)N * 96;

    hipMemsetAsync(cnt, 0, (size_t)N * sizeof(int), stream);

    const int mt = (N + 63) / 64;
    const int et = (E + 255) / 256;

    // weight prep (once) + CSR bucketing
    prep_kernel<<<1, 256, 0, stream>>>(Wb, We, Wf0, Wf1, wbwe16, wf0t16, wf1t16);
    count_kernel<<<et, 256, 0, stream>>>(dst, cnt, rank, E);
    scan_kernel<<<1, 1024, 0, stream>>>(cnt, offv, N);
    scatter_kernel<<<et, 256, 0, stream>>>(dst, src, offv, rank, eidx, srcs, dsts, E);

    // qkv16 = bf16( LN(feat) @ [Wq|Wk|Wv] )  (LN fused; bf16-only output)
    mgemm_kernel<1,1,0,0,0><<<dim3(mt, 3), 256, 0, stream>>>(
        feat, 96, Wq, Wk, Wv, 96, bq, bk, bv, g_n0, b_n0,
        nullptr, nullptr, nullptr, 0, qkv16, N, 96);

    // fused edge tile pass (CSR slot order, bf16 q/k, global-L1 weights)
    edge_tile_kernel<<<(E + 63) / 64, 256, 0, stream>>>(edge, qkv16, eidx, srcs, dsts,
                                             wbwe16, wf0t16, wf1t16,
                                             be, bb, bf0, bf1,
                                             g_e0, b_e0, g_e1, b_e1,
                                             exve16, eoutp, E);

    // gather per node -> normalized agg16[N,128] (bf16)
    gather_kernel<<<(N + 3) / 4, 256, 0, stream>>>(exve16, qkv16, srcs, offv, cnt, agg16, N);

    // h_pre = feat*(1+w) + agg @ Wvv + bvv   (bf16 A)
    mgemm_kernel<0,0,1,0,1><<<dim3(mt, 1), 256, 0, stream>>>(
        agg16, 128, Wvv, Wvv, Wvv, 96, bvv, bvv, bvv, nullptr, nullptr,
        feat, wsc, hp, 96, nullptr, N, 128);
    // t = relu(LN(hp) @ Wm0 + bm0)   (LN fused)
    mgemm_kernel<0,1,0,1,0><<<dim3(mt, 2), 256, 0, stream>>>(
        hp, 96, Wm0, Wm0, Wm0, 192, bm0, bm0, bm0, g_m, b_m,
        nullptr, nullptr, tbuf, 192, nullptr, N, 96);
    // h_out = hp + t @ Wm1 + bm1
    mgemm_kernel<0,0,0,0,1><<<dim3(mt, 1), 256, 0, stream>>>(
        tbuf, 192, Wm1, Wm1, Wm1, 96, bm1, bm1, bm1, nullptr, nullptr,
        hp, nullptr, hout, 96, nullptr, N, 192);
}

// Round 18
// 783.866 us; speedup vs baseline: 1.4207x; 1.0446x over previous
//
#include <hip/hip_runtime.h>
#include <cstdint>
#include <cstddef>

// ---------------------------------------------------------------------------
// EGT layer.  N nodes (DIM=96, H=32, HD=3), E edges.
// CSR slot metadata packed as int4 slotinfo[slot]={eidx,src,dst,0} (one 16B
// scattered store in scatter; one L1-broadcast load per slot in edge_tile).
// edge_tile_kernel: 64 CSR slots/block, global-L1 bf16 weights, 29.7KB LDS.
// qkv bf16-only; gather contiguous; mgemm MFMA with fused LN.
// ---------------------------------------------------------------------------

typedef short  s16x8 __attribute__((ext_vector_type(8)));
typedef short  s16x4 __attribute__((ext_vector_type(4)));
typedef float  f32x4 __attribute__((ext_vector_type(4)));

__device__ __forceinline__ unsigned short f2b(float x) {
    union { float f; unsigned u; } v; v.f = x;
    unsigned r = v.u + 0x7FFF + ((v.u >> 16) & 1);   // RNE
    return (unsigned short)(r >> 16);
}
__device__ __forceinline__ float b2f(unsigned short u) {
    union { unsigned u; float f; } v; v.u = ((unsigned)u) << 16; return v.f;
}

// ---------------- MFMA node GEMM ----------------
template<int MULTI, int LNA, int A16, int RELU, int RES>
__global__ __launch_bounds__(256) void mgemm_kernel(
    const void* __restrict__ Av, int lda,
    const float* __restrict__ B0, const float* __restrict__ B1,
    const float* __restrict__ B2, int ldb,
    const float* __restrict__ bias0, const float* __restrict__ bias1,
    const float* __restrict__ bias2,
    const float* __restrict__ lng, const float* __restrict__ lnbv,
    const float* __restrict__ resid, const float* __restrict__ wptr,
    float* __restrict__ C, int ldc, unsigned short* __restrict__ C16,
    int M, int K)
{
    __shared__ unsigned short sAL[64 * 200];
    __shared__ unsigned short sB[96 * 40];

    const int tid = threadIdx.x;
    const int m0 = blockIdx.x * 64;
    const int y  = blockIdx.y;
    const float* B = MULTI ? (y == 0 ? B0 : (y == 1 ? B1 : B2)) : B0;
    const int nbB = MULTI ? 0 : y * 96;
    const int nbC = y * 96;
    const int w = tid >> 6, l = tid & 63, fr = l & 15, kg = l >> 4;
    const int KP = K + 8;

    if (LNA) {
        const float* Af = (const float*)Av;
        const int row = 16 * w + fr;
        const int grow = m0 + row;
        float x[24];
        if (grow < M) {
            #pragma unroll
            for (int t = 0; t < 6; t++)
                *(float4*)&x[t * 4] = *(const float4*)(Af + (size_t)grow * lda + 24 * kg + t * 4);
        } else {
            #pragma unroll
            for (int t = 0; t < 24; t++) x[t] = 0.f;
        }
        float s = 0.f;
        #pragma unroll
        for (int t = 0; t < 24; t++) s += x[t];
        s += __shfl_xor(s, 16, 64); s += __shfl_xor(s, 32, 64);
        float mu = s * (1.f / 96.f);
        float v2 = 0.f;
        #pragma unroll
        for (int t = 0; t < 24; t++) { float d = x[t] - mu; v2 += d * d; }
        v2 += __shfl_xor(v2, 16, 64); v2 += __shfl_xor(v2, 32, 64);
        float rs = rsqrtf(v2 * (1.f / 96.f) + 1e-5f);
        #pragma unroll
        for (int t3 = 0; t3 < 3; t3++) {
            s16x8 yv;
            #pragma unroll
            for (int u = 0; u < 8; u++) {
                int cidx = 24 * kg + t3 * 8 + u;
                yv[u] = (short)f2b((x[t3 * 8 + u] - mu) * rs * lng[cidx] + lnbv[cidx]);
            }
            *(s16x8*)&sAL[row * KP + 24 * kg + t3 * 8] = yv;
        }
    } else {
        const int nseg = K >> 3;
        for (int idx = tid; idx < 64 * nseg; idx += 256) {
            int row = idx / nseg, k8 = (idx - row * nseg) * 8;
            int grow = m0 + row;
            s16x8 a8 = (s16x8){0, 0, 0, 0, 0, 0, 0, 0};
            if (grow < M) {
                if (A16) {
                    a8 = *(const s16x8*)((const unsigned short*)Av + (size_t)grow * lda + k8);
                } else {
                    const float* Af = (const float*)Av;
                    float4 v0 = *(const float4*)(Af + (size_t)grow * lda + k8);
                    float4 v1 = *(const float4*)(Af + (size_t)grow * lda + k8 + 4);
                    a8[0] = (short)f2b(v0.x); a8[1] = (short)f2b(v0.y);
                    a8[2] = (short)f2b(v0.z); a8[3] = (short)f2b(v0.w);
                    a8[4] = (short)f2b(v1.x); a8[5] = (short)f2b(v1.y);
                    a8[6] = (short)f2b(v1.z); a8[7] = (short)f2b(v1.w);
                }
            }
            *(s16x8*)&sAL[row * KP + k8] = a8;
        }
    }

    f32x4 acc[6];
    #pragma unroll
    for (int i = 0; i < 6; i++) acc[i] = (f32x4){0.f, 0.f, 0.f, 0.f};

    for (int kc = 0; kc < K; kc += 32) {
        #pragma unroll
        for (int r = 0; r < 3; r++) {
            int idx = tid + 256 * r;
            int k = idx / 24, n4 = (idx - k * 24) * 4;
            float4 v = *(const float4*)(B + (size_t)(kc + k) * ldb + nbB + n4);
            sB[(n4 + 0) * 40 + k] = f2b(v.x);
            sB[(n4 + 1) * 40 + k] = f2b(v.y);
            sB[(n4 + 2) * 40 + k] = f2b(v.z);
            sB[(n4 + 3) * 40 + k] = f2b(v.w);
        }
        __syncthreads();
        {
            s16x8 a = *(s16x8*)&sAL[(16 * w + fr) * KP + kc + kg * 8];
            #pragma unroll
            for (int nt = 0; nt < 6; nt++) {
                s16x8 b = *(s16x8*)&sB[(16 * nt + fr) * 40 + kg * 8];
                acc[nt] = __builtin_amdgcn_mfma_f32_16x16x32_bf16(a, b, acc[nt], 0, 0, 0);
            }
        }
        __syncthreads();
    }

    float scale = 1.f;
    if (RES) scale = wptr ? (1.f + wptr[0]) : 1.f;
    const float* biasp = MULTI ? (y == 0 ? bias0 : (y == 1 ? bias1 : bias2)) : bias0;
    const int bbase = MULTI ? 0 : nbB;

    #pragma unroll
    for (int nt = 0; nt < 6; nt++) {
        int cl = nt * 16 + fr;
        float bv = biasp[bbase + cl];
        int gcol = nbC + cl;
        #pragma unroll
        for (int r = 0; r < 4; r++) {
            int row = m0 + 16 * w + 4 * kg + r;
            if (row >= M) continue;
            float v = acc[nt][r] + bv;
            if (RELU) v = fmaxf(v, 0.f);
            if (MULTI) {
                C16[(size_t)row * 288 + gcol] = f2b(v);
            } else {
                if (RES) v += scale * resid[(size_t)row * ldc + gcol];
                C[(size_t)row * ldc + gcol] = v;
            }
        }
    }
}

// ---------------- prep: edge weights -> bf16 [N][K] layouts (once) ---------
__global__ __launch_bounds__(256) void prep_kernel(
    const float* __restrict__ Wb, const float* __restrict__ We,
    const float* __restrict__ Wf0, const float* __restrict__ Wf1,
    unsigned short* __restrict__ WbWe16, unsigned short* __restrict__ Wf0T16,
    unsigned short* __restrict__ Wf1T16)
{
    const int t = threadIdx.x;
    for (int i = t; i < 2048; i += 256) {
        int n = i >> 5, k = i & 31;
        float v = (n < 32) ? Wb[k * 32 + n] : We[k * 32 + (n - 32)];
        WbWe16[i] = f2b(v);
    }
    for (int i = t; i < 2048; i += 256) {
        int n = i >> 5, k = i & 31;
        Wf0T16[i] = f2b(Wf0[k * 64 + n]);
    }
    for (int i = t; i < 2048; i += 256) {
        int n = i >> 6, k = i & 63;
        Wf1T16[i] = f2b(Wf1[k * 32 + n]);
    }
}

// ---------------- CSR bucketing ----------------
__global__ __launch_bounds__(256) void count_kernel(
    const int* __restrict__ dst, int* __restrict__ cnt,
    int* __restrict__ rank, int E)
{
    int i = blockIdx.x * 256 + threadIdx.x;
    if (i < E) rank[i] = atomicAdd(&cnt[dst[i]], 1);
}

__global__ __launch_bounds__(1024) void scan_kernel(
    const int* __restrict__ cnt, int* __restrict__ off, int N)
{
    __shared__ int s[1024];
    const int tid = threadIdx.x;
    const int chunk = (N + 1023) >> 10;
    const int lo = tid * chunk;
    const int hi = min(lo + chunk, N);
    int sum = 0;
    for (int i = lo; i < hi; i++) sum += cnt[i];
    s[tid] = sum;
    __syncthreads();
    for (int d = 1; d < 1024; d <<= 1) {
        int v = (tid >= d) ? s[tid - d] : 0;
        __syncthreads();
        s[tid] += v;
        __syncthreads();
    }
    int base = (tid == 0) ? 0 : s[tid - 1];
    for (int i = lo; i < hi; i++) {
        off[i] = base;
        base += cnt[i];
    }
}

// scatter: one 16B scattered store per edge -- slotinfo[p]={eidx,src,dst,0}
__global__ __launch_bounds__(256) void scatter_kernel(
    const int* __restrict__ dst, const int* __restrict__ src,
    const int* __restrict__ off, const int* __restrict__ rank,
    int4* __restrict__ slotinfo, int E)
{
    int i = blockIdx.x * 256 + threadIdx.x;
    if (i < E) {
        int d = dst[i];
        int p = off[d] + rank[i];
        slotinfo[p] = make_int4(i, src[i], d, 0);
    }
}

// ---------------- edge tile kernel: 64 CSR slots per block ------------------
// exve16 (bf16) layout: [slot][64] = {ex[0..32), ve[32..64)}
__global__ __launch_bounds__(256, 5) void edge_tile_kernel(
    const float* __restrict__ edge, const unsigned short* __restrict__ qkv16,
    const int4* __restrict__ slotinfo,
    const unsigned short* __restrict__ WbWe16,
    const unsigned short* __restrict__ Wf0T16,
    const unsigned short* __restrict__ Wf1T16,
    const float* __restrict__ be, const float* __restrict__ bb,
    const float* __restrict__ bf0, const float* __restrict__ bf1,
    const float* __restrict__ ge0, const float* __restrict__ be0,
    const float* __restrict__ ge1, const float* __restrict__ be1,
    unsigned short* __restrict__ exve16, float* __restrict__ eout, int E)
{
    __shared__ float          sEV[64 * 36];   // ev -> er
    __shared__ unsigned short sQK[64 * 44];   // qk bf16 (pad 44)
    __shared__ unsigned short sA [64 * 40];   // ew/en bf16
    __shared__ unsigned short sX [64 * 76];   // ex|ve then F (pad 76)
    // total 29,696 B -> 5 blocks/CU

    const int tid = threadIdx.x;
    const long long e0 = (long long)blockIdx.x * 64;
    const int w  = tid >> 6;
    const int l  = tid & 63;
    const int fr = l & 15;
    const int kg = l >> 4;

    // ---- S1a: fused score from bf16 qkv16 (CSR order, q[dst] hot) ----
    {
        const int row = tid >> 2;
        const int j   = tid & 3;
        long long s = e0 + row;
        float qv[24], kv[24];
        if (s < E) {
            int4 si = slotinfo[s];               // L1 broadcast: 4 thr/slot
            const unsigned short* qp = qkv16 + (size_t)si.z * 288 + 24 * j;
            const unsigned short* kp = qkv16 + (size_t)si.y * 288 + 96 + 24 * j;
            #pragma unroll
            for (int t = 0; t < 3; t++) {
                s16x8 qa = *(const s16x8*)(qp + 8 * t);
                s16x8 ka = *(const s16x8*)(kp + 8 * t);
                #pragma unroll
                for (int u = 0; u < 8; u++) {
                    qv[8 * t + u] = b2f((unsigned short)qa[u]);
                    kv[8 * t + u] = b2f((unsigned short)ka[u]);
                }
            }
        } else {
            #pragma unroll
            for (int t = 0; t < 24; t++) { qv[t] = 0.f; kv[t] = 0.f; }
        }
        s16x8 qkb;
        #pragma unroll
        for (int t = 0; t < 8; t++) {
            float d = kv[3*t]*qv[3*t] + kv[3*t+1]*qv[3*t+1] + kv[3*t+2]*qv[3*t+2];
            qkb[t] = (short)f2b(0.5f * d);
        }
        *(s16x8*)&sQK[row * 44 + 8 * j] = qkb;
    }
    // ---- S1b: stage ev rows (via slotinfo.x) ----
    #pragma unroll
    for (int rr = 0; rr < 2; rr++) {
        int idx = tid + 256 * rr;
        int row = idx >> 3, c4 = (idx & 7) * 4;
        long long s = e0 + row;
        float4 v = make_float4(0.f, 0.f, 0.f, 0.f);
        if (s < E) {
            int ge = slotinfo[s].x;
            v = *(const float4*)(edge + (size_t)ge * 32 + c4);
        }
        *(float4*)&sEV[row * 36 + c4] = v;
    }
    __syncthreads();

    // ---- S2: LN1 -> ew rows (bf16) in sA (wave-local rows) ----
    {
        const int row = 16 * w + (tid & 15);
        const int q = (tid & 63) >> 4;
        float x[8];
        *(float4*)&x[0] = *(float4*)&sEV[row * 36 + 8 * q];
        *(float4*)&x[4] = *(float4*)&sEV[row * 36 + 8 * q + 4];
        float s = x[0] + x[1] + x[2] + x[3] + x[4] + x[5] + x[6] + x[7];
        s += __shfl_xor(s, 16, 64); s += __shfl_xor(s, 32, 64);
        float mu = s * (1.f / 32.f);
        float v2 = 0.f;
        #pragma unroll
        for (int i = 0; i < 8; i++) { float d = x[i] - mu; v2 += d * d; }
        v2 += __shfl_xor(v2, 16, 64); v2 += __shfl_xor(v2, 32, 64);
        float rs = rsqrtf(v2 * (1.f / 32.f) + 1e-5f);
        float4 g1 = *(const float4*)(ge0 + 8 * q), g2 = *(const float4*)(ge0 + 8 * q + 4);
        float4 b1 = *(const float4*)(be0 + 8 * q), b2 = *(const float4*)(be0 + 8 * q + 4);
        float gg[8] = {g1.x, g1.y, g1.z, g1.w, g2.x, g2.y, g2.z, g2.w};
        float bs[8] = {b1.x, b1.y, b1.z, b1.w, b2.x, b2.y, b2.z, b2.w};
        s16x8 y;
        #pragma unroll
        for (int i = 0; i < 8; i++)
            y[i] = (short)f2b((x[i] - mu) * rs * gg[i] + bs[i]);
        *(s16x8*)&sA[row * 40 + 8 * q] = y;
    }
    __builtin_amdgcn_wave_barrier();

    // ---- S3: GEMM1 (MFMA)  [64][64 = sc|veh] = ew @ [Wb|We] (B from L1) ----
    f32x4 acc[4];
    {
        s16x8 a = *(s16x8*)&sA[(16 * w + fr) * 40 + kg * 8];
        #pragma unroll
        for (int nt = 0; nt < 4; nt++) {
            s16x8 b = *(const s16x8*)(WbWe16 + (16 * nt + fr) * 32 + kg * 8);
            f32x4 z = {0.f, 0.f, 0.f, 0.f};
            acc[nt] = __builtin_amdgcn_mfma_f32_16x16x32_bf16(a, b, z, 0, 0, 0);
        }
    }

    // ---- S4: epilogue1 (ex|ve -> sX; er -> sEV), all wave-local rows ----
    #pragma unroll
    for (int nt = 0; nt < 2; nt++) {
        int col = nt * 16 + fr;
        float bbv = bb[col];
        #pragma unroll
        for (int r = 0; r < 4; r++) {
            int row = 16 * w + 4 * kg + r;
            float sc = acc[nt][r] + b2f(sQK[row * 44 + col]) + bbv;
            sX[row * 76 + col] = f2b(__expf(sc));
            float er = sc + sEV[row * 36 + col];
            sEV[row * 36 + col] = er;
        }
    }
    #pragma unroll
    for (int nt = 2; nt < 4; nt++) {
        int col = (nt - 2) * 16 + fr;
        float bev = be[col];
        #pragma unroll
        for (int r = 0; r < 4; r++) {
            int row = 16 * w + 4 * kg + r;
            sX[row * 76 + 32 + col] = f2b(acc[nt][r] + bev);
        }
    }
    __syncthreads();

    // ---- S5a: copy sX -> exve16 (contiguous at slot); S5b: LN2 -> sA ----
    #pragma unroll
    for (int rr = 0; rr < 2; rr++) {
        int idx = tid + 256 * rr;
        int row = idx >> 3, c8 = (idx & 7) * 8;
        long long s = e0 + row;
        if (s < E)
            *(s16x8*)(exve16 + (size_t)s * 64 + c8) = *(s16x8*)&sX[row * 76 + c8];
    }
    {
        const int row = 16 * w + (tid & 15);
        const int q = (tid & 63) >> 4;
        float x[8];
        *(float4*)&x[0] = *(float4*)&sEV[row * 36 + 8 * q];
        *(float4*)&x[4] = *(float4*)&sEV[row * 36 + 8 * q + 4];
        float s = x[0] + x[1] + x[2] + x[3] + x[4] + x[5] + x[6] + x[7];
        s += __shfl_xor(s, 16, 64); s += __shfl_xor(s, 32, 64);
        float mu = s * (1.f / 32.f);
        float v2 = 0.f;
        #pragma unroll
        for (int i = 0; i < 8; i++) { float d = x[i] - mu; v2 += d * d; }
        v2 += __shfl_xor(v2, 16, 64); v2 += __shfl_xor(v2, 32, 64);
        float rs = rsqrtf(v2 * (1.f / 32.f) + 1e-5f);
        float4 g1 = *(const float4*)(ge1 + 8 * q), g2 = *(const float4*)(ge1 + 8 * q + 4);
        float4 b1 = *(const float4*)(be1 + 8 * q), b2 = *(const float4*)(be1 + 8 * q + 4);
        float gg[8] = {g1.x, g1.y, g1.z, g1.w, g2.x, g2.y, g2.z, g2.w};
        float bs[8] = {b1.x, b1.y, b1.z, b1.w, b2.x, b2.y, b2.z, b2.w};
        s16x8 y;
        #pragma unroll
        for (int i = 0; i < 8; i++)
            y[i] = (short)f2b((x[i] - mu) * rs * gg[i] + bs[i]);
        *(s16x8*)&sA[row * 40 + 8 * q] = y;
    }
    __syncthreads();   // sX must be fully copied out before S6 overwrites it

    // ---- S6: GEMM2 (MFMA)  F[64][64] = relu(en @ Wf0 + bf0) -> sX ----
    {
        s16x8 a = *(s16x8*)&sA[(16 * w + fr) * 40 + kg * 8];
        #pragma unroll
        for (int nt = 0; nt < 4; nt++) {
            s16x8 b = *(const s16x8*)(Wf0T16 + (16 * nt + fr) * 32 + kg * 8);
            f32x4 z = {0.f, 0.f, 0.f, 0.f};
            f32x4 a2 = __builtin_amdgcn_mfma_f32_16x16x32_bf16(a, b, z, 0, 0, 0);
            int col = nt * 16 + fr;
            float b0v = bf0[col];
            #pragma unroll
            for (int r = 0; r < 4; r++) {
                int row = 16 * w + 4 * kg + r;
                sX[row * 76 + col] = f2b(fmaxf(a2[r] + b0v, 0.f));
            }
        }
    }
    __builtin_amdgcn_wave_barrier();

    // ---- S7: GEMM3 (MFMA)  out[64][32] = F @ Wf1 + er + bf1 -> sEV ----
    {
        s16x8 a0 = *(s16x8*)&sX[(16 * w + fr) * 76 + kg * 8];
        s16x8 a1 = *(s16x8*)&sX[(16 * w + fr) * 76 + 32 + kg * 8];
        #pragma unroll
        for (int nt = 0; nt < 2; nt++) {
            s16x8 b0 = *(const s16x8*)(Wf1T16 + (16 * nt + fr) * 64 + kg * 8);
            s16x8 b1 = *(const s16x8*)(Wf1T16 + (16 * nt + fr) * 64 + 32 + kg * 8);
            f32x4 z = {0.f, 0.f, 0.f, 0.f};
            f32x4 t = __builtin_amdgcn_mfma_f32_16x16x32_bf16(a0, b0, z, 0, 0, 0);
            t = __builtin_amdgcn_mfma_f32_16x16x32_bf16(a1, b1, t, 0, 0, 0);
            int col = nt * 16 + fr;
            float bf1v = bf1[col];
            #pragma unroll
            for (int r = 0; r < 4; r++) {
                int row = 16 * w + 4 * kg + r;
                float out = t[r] + sEV[row * 36 + col] + bf1v;
                sEV[row * 36 + col] = out;
            }
        }
    }
    __syncthreads();

    // ---- S8: copy sEV[:, 0..32) -> eout[slotinfo.x] ----
    #pragma unroll
    for (int rr = 0; rr < 2; rr++) {
        int idx = tid + 256 * rr;
        int row = idx >> 3, c4 = (idx & 7) * 4;
        long long s = e0 + row;
        if (s < E) {
            int ge = slotinfo[s].x;
            *(float4*)(eout + (size_t)ge * 32 + c4) = *(float4*)&sEV[row * 36 + c4];
        }
    }
}

// ---------------- gather: wave/node, 2 edges in flight per half ------------
__global__ __launch_bounds__(256) void gather_kernel(
    const unsigned short* __restrict__ exve16, const unsigned short* __restrict__ qkv16,
    const int4* __restrict__ slotinfo, const int* __restrict__ off,
    const int* __restrict__ cnt, unsigned short* __restrict__ agg16, int N)
{
    __shared__ unsigned short sV16[4][2][2][96];
    __shared__ unsigned short sE16[4][2][2][64];
    const int wave = threadIdx.x >> 6;
    const int lane = threadIdx.x & 63;
    const int head = lane & 31;
    const int half = lane >> 5;
    int n = blockIdx.x * 4 + wave;
    if (n >= N) return;
    const int o = off[n], d = cnt[n];
    float a0 = 0.f, a1 = 0.f, a2 = 0.f, a3 = 0.f, den = 0.f;
    for (int i = half; i < d; i += 4) {
        const int i2 = i + 2;
        {
            int sn = slotinfo[o + i].y;
            const unsigned short* vr = qkv16 + (size_t)sn * 288 + 192;
            const unsigned short* er = exve16 + (size_t)(o + i) * 64;
            if (head < 12)
                *(s16x8*)&sV16[wave][half][0][head * 8] = *(const s16x8*)(vr + head * 8);
            else if (head >= 24)
                *(s16x8*)&sE16[wave][half][0][(head - 24) * 8] = *(const s16x8*)(er + (head - 24) * 8);
        }
        if (i2 < d) {
            int sn = slotinfo[o + i2].y;
            const unsigned short* vr = qkv16 + (size_t)sn * 288 + 192;
            const unsigned short* er = exve16 + (size_t)(o + i2) * 64;
            if (head < 12)
                *(s16x8*)&sV16[wave][half][1][head * 8] = *(const s16x8*)(vr + head * 8);
            else if (head >= 24)
                *(s16x8*)&sE16[wave][half][1][(head - 24) * 8] = *(const s16x8*)(er + (head - 24) * 8);
        }
        __builtin_amdgcn_wave_barrier();
        {
            float ex = b2f(sE16[wave][half][0][head]);
            float vv = b2f(sE16[wave][half][0][32 + head]);
            a0 += ex * b2f(sV16[wave][half][0][head * 3]);
            a1 += ex * b2f(sV16[wave][half][0][head * 3 + 1]);
            a2 += ex * b2f(sV16[wave][half][0][head * 3 + 2]);
            a3 += ex * vv;
            den += ex;
        }
        if (i2 < d) {
            float ex = b2f(sE16[wave][half][1][head]);
            float vv = b2f(sE16[wave][half][1][32 + head]);
            a0 += ex * b2f(sV16[wave][half][1][head * 3]);
            a1 += ex * b2f(sV16[wave][half][1][head * 3 + 1]);
            a2 += ex * b2f(sV16[wave][half][1][head * 3 + 2]);
            a3 += ex * vv;
            den += ex;
        }
        __builtin_amdgcn_wave_barrier();
    }
    a0 += __shfl_xor(a0, 32, 64);
    a1 += __shfl_xor(a1, 32, 64);
    a2 += __shfl_xor(a2, 32, 64);
    a3 += __shfl_xor(a3, 32, 64);
    den += __shfl_xor(den, 32, 64);
    if (half == 0) {
        float sc = (d > 0) ? 1.f / den : 0.f;
        s16x4 ov;
        ov[0] = (short)f2b(a0 * sc);
        ov[1] = (short)f2b(a1 * sc);
        ov[2] = (short)f2b(a2 * sc);
        ov[3] = (short)f2b(a3 * sc);
        *(s16x4*)(agg16 + (size_t)n * 128 + head * 4) = ov;
    }
}

// ---------------------------------------------------------------------------
extern "C" void kernel_launch(void* const* d_in, const int* in_sizes, int n_in,
                              void* d_out, int out_size, void* d_ws, size_t ws_size,
                              hipStream_t stream)
{
    (void)n_in; (void)out_size; (void)ws_size;
    const float* feat = (const float*)d_in[0];
    const float* edge = (const float*)d_in[1];
    const float* Wq   = (const float*)d_in[2];
    const float* bq   = (const float*)d_in[3];
    const float* Wk   = (const float*)d_in[4];
    const float* bk   = (const float*)d_in[5];
    const float* Wv   = (const float*)d_in[6];
    const float* bv   = (const float*)d_in[7];
    const float* We   = (const float*)d_in[8];
    const float* be   = (const float*)d_in[9];
    const float* Wb   = (const float*)d_in[10];
    const float* bb   = (const float*)d_in[11];
    const float* Wvv  = (const float*)d_in[12];
    const float* bvv  = (const float*)d_in[13];
    const float* Wf0  = (const float*)d_in[14];
    const float* bf0  = (const float*)d_in[15];
    const float* Wf1  = (const float*)d_in[16];
    const float* bf1  = (const float*)d_in[17];
    const float* Wm0  = (const float*)d_in[18];
    const float* bm0  = (const float*)d_in[19];
    const float* Wm1  = (const float*)d_in[20];
    const float* bm1  = (const float*)d_in[21];
    const float* g_n0 = (const float*)d_in[22];
    const float* b_n0 = (const float*)d_in[23];
    const float* g_e0 = (const float*)d_in[24];
    const float* b_e0 = (const float*)d_in[25];
    const float* g_e1 = (const float*)d_in[26];
    const float* b_e1 = (const float*)d_in[27];
    const float* g_m  = (const float*)d_in[28];
    const float* b_m  = (const float*)d_in[29];
    const float* wsc  = (const float*)d_in[30];
    const int*   src  = (const int*)d_in[31];
    const int*   dst  = (const int*)d_in[32];

    const int N = in_sizes[0] / 96;
    const int E = in_sizes[1] / 32;

    float* ws    = (float*)d_ws;
    float* hp    = ws;                                      // N*96 f32
    float* tbuf  = hp + (size_t)N * 96;                     // N*192 f32
    unsigned short* agg16 = (unsigned short*)(tbuf + (size_t)N * 192); // N*128 bf16
    unsigned short* qkv16 = agg16 + (size_t)N * 128;        // N*288 bf16
    unsigned short* exve16 = qkv16 + (size_t)N * 288;       // E*64 bf16
    unsigned short* wbwe16 = exve16 + (size_t)E * 64;       // 2048
    unsigned short* wf0t16 = wbwe16 + 2048;                 // 2048
    unsigned short* wf1t16 = wf0t16 + 2048;                 // 2048
    int4*  slotinfo = (int4*)(wf1t16 + 2048);               // E int4 (16B aligned)
    int*   rank  = (int*)(slotinfo + E);                    // E
    int*   cnt   = rank + E;                                // N
    int*   offv  = cnt + N;                                 // N
    float* hout  = (float*)d_out;
    float* eoutp = (float*)d_out + (size_t)N * 96;

    hipMemsetAsync(cnt, 0, (size_t)N * sizeof(int), stream);

    const int mt = (N + 63) / 64;
    const int et = (E + 255) / 256;

    // weight prep (once) + CSR bucketing
    prep_kernel<<<1, 256, 0, stream>>>(Wb, We, Wf0, Wf1, wbwe16, wf0t16, wf1t16);
    count_kernel<<<et, 256, 0, stream>>>(dst, cnt, rank, E);
    scan_kernel<<<1, 1024, 0, stream>>>(cnt, offv, N);
    scatter_kernel<<<et, 256, 0, stream>>>(dst, src, offv, rank, slotinfo, E);

    // qkv16 = bf16( LN(feat) @ [Wq|Wk|Wv] )  (LN fused; bf16-only output)
    mgemm_kernel<1,1,0,0,0><<<dim3(mt, 3), 256, 0, stream>>>(
        feat, 96, Wq, Wk, Wv, 96, bq, bk, bv, g_n0, b_n0,
        nullptr, nullptr, nullptr, 0, qkv16, N, 96);

    // fused edge tile pass (CSR slot order, bf16 q/k, global-L1 weights)
    edge_tile_kernel<<<(E + 63) / 64, 256, 0, stream>>>(edge, qkv16, slotinfo,
                                             wbwe16, wf0t16, wf1t16,
                                             be, bb, bf0, bf1,
                                             g_e0, b_e0, g_e1, b_e1,
                                             exve16, eoutp, E);

    // gather per node -> normalized agg16[N,128] (bf16)
    gather_kernel<<<(N + 3) / 4, 256, 0, stream>>>(exve16, qkv16, slotinfo, offv, cnt, agg16, N);

    // h_pre = feat*(1+w) + agg @ Wvv + bvv   (bf16 A)
    mgemm_kernel<0,0,1,0,1><<<dim3(mt, 1), 256, 0, stream>>>(
        agg16, 128, Wvv, Wvv, Wvv, 96, bvv, bvv, bvv, nullptr, nullptr,
        feat, wsc, hp, 96, nullptr, N, 128);
    // t = relu(LN(hp) @ Wm0 + bm0)   (LN fused)
    mgemm_kernel<0,1,0,1,0><<<dim3(mt, 2), 256, 0, stream>>>(
        hp, 96, Wm0, Wm0, Wm0, 192, bm0, bm0, bm0, g_m, b_m,
        nullptr, nullptr, tbuf, 192, nullptr, N, 96);
    // h_out = hp + t @ Wm1 + bm1
    mgemm_kernel<0,0,0,0,1><<<dim3(mt, 1), 256, 0, stream>>>(
        tbuf, 192, Wm1, Wm1, Wm1, 96, bm1, bm1, bm1, nullptr, nullptr,
        hp, nullptr, hout, 96, nullptr, N, 192);
}